// Round 11
// baseline (752.369 us; speedup 1.0000x reference)
//
#include <hip/hip_runtime.h>
#include <hip/hip_bf16.h>
#include <math.h>

#define E_DIM 384
#define N_HEAD 6
#define HEAD_SZ 64
#define SEQ 256
#define BATCH 16
#define NTOK 4096
#define NLAYER 6
#define VOCAB 50257
#define VPAD 50304          // 393*128
#define QKV_N 1152          // 3*E
#define NBH 96              // BATCH*N_HEAD

typedef __attribute__((ext_vector_type(8))) short bf16x8;
typedef __attribute__((ext_vector_type(4))) float f32x4;

__device__ __forceinline__ void gload16(const void* g, void* l) {
    __builtin_amdgcn_global_load_lds((const __attribute__((address_space(1))) char*)g,
                                     (__attribute__((address_space(3))) char*)l, 16, 0, 0);
}

__device__ __forceinline__ unsigned short bfbits(float x) {
    __hip_bfloat16 h = __float2bfloat16(x);
    return *reinterpret_cast<unsigned short*>(&h);
}

// ---------------- prep: weight transposes + embedding + LN1, one dispatch ------
__device__ __forceinline__ void tconv_tile(const float* __restrict__ src,
                                           __hip_bfloat16* __restrict__ dst,
                                           int K, int N, int n0, int k0) {
    __shared__ float tbuf[64][65];
    int c = threadIdx.x & 63, r4 = threadIdx.x >> 6;
#pragma unroll
    for (int i = 0; i < 16; ++i) {
        int r = r4 * 16 + i;
        float v = 0.f;
        if (n0 + c < N) v = src[(size_t)(k0 + r) * N + n0 + c];
        tbuf[r][c] = v;
    }
    __syncthreads();
#pragma unroll
    for (int i = 0; i < 16; ++i) {
        int rn = r4 * 16 + i;
        dst[(size_t)(n0 + rn) * K + k0 + c] = __float2bfloat16(tbuf[c][rn]);
    }
}

__global__ __launch_bounds__(256) void prep_kernel(const float* __restrict__ Wq,
                                                   const float* __restrict__ Wk,
                                                   const float* __restrict__ Wv,
                                                   const float* __restrict__ Wo,
                                                   const float* __restrict__ Wm,
                                                   const float* __restrict__ Wlm,
                                                   __hip_bfloat16* __restrict__ WtL,
                                                   __hip_bfloat16* __restrict__ WtLM,
                                                   const int* __restrict__ idx,
                                                   const float* __restrict__ tok,
                                                   const float* __restrict__ pos,
                                                   const float* __restrict__ g,
                                                   const float* __restrict__ b,
                                                   float* __restrict__ x,
                                                   __hip_bfloat16* __restrict__ h) {
    int bid = blockIdx.x;
    if (bid < 1080) {              // per-layer weights: 30 z-slices x 36 tiles
        int z = bid / 36, rem = bid - z * 36;
        int bx = rem % 6, by = rem / 6;
        int l = z / 5, t = z - l * 5;
        const float* src;
        int dstoff;
        switch (t) {
            case 0: src = Wq; dstoff = 0;    break;
            case 1: src = Wk; dstoff = 384;  break;
            case 2: src = Wv; dstoff = 768;  break;
            case 3: src = Wo; dstoff = 1152; break;
            default: src = Wm; dstoff = 1536;
        }
        src += (size_t)l * E_DIM * E_DIM;
        __hip_bfloat16* dst = WtL + ((size_t)l * 1920 + dstoff) * E_DIM;
        tconv_tile(src, dst, E_DIM, E_DIM, bx * 64, by * 64);
    } else if (bid < 1080 + 786 * 6) {   // LM head transpose
        int b2 = bid - 1080;
        int bx = b2 % 786, by = b2 / 786;
        tconv_tile(Wlm, WtLM, E_DIM, VOCAB, bx * 64, by * 64);
    } else {                       // embedding + LN1: 1024 blocks x 4 rows
        int rb = bid - (1080 + 786 * 6);
        int lane = threadIdx.x & 63;
        int w = threadIdx.x >> 6;
        int row = rb * 4 + w;
        int t = row & (SEQ - 1);
        const float* tr = tok + (size_t)idx[row] * E_DIM;
        const float* pr = pos + (size_t)t * E_DIM;
        float* xr = x + (size_t)row * E_DIM;
        float v[6];
        float s = 0.f;
#pragma unroll
        for (int c = 0; c < 6; ++c) {
            int e = lane + 64 * c;
            v[c] = tr[e] + pr[e];
            xr[e] = v[c];
            s += v[c];
        }
#pragma unroll
        for (int off = 32; off > 0; off >>= 1) s += __shfl_xor(s, off);
        float mu = s * (1.0f / E_DIM);
        float s2 = 0.f;
#pragma unroll
        for (int c = 0; c < 6; ++c) { float d = v[c] - mu; s2 += d * d; }
#pragma unroll
        for (int off = 32; off > 0; off >>= 1) s2 += __shfl_xor(s2, off);
        float rstd = rsqrtf(s2 * (1.0f / E_DIM) + 1e-5f);
        __hip_bfloat16* hr = h + (size_t)row * E_DIM;
#pragma unroll
        for (int c = 0; c < 6; ++c) {
            int e = lane + 64 * c;
            hr[e] = __float2bfloat16((v[c] - mu) * rstd * g[e] + b[e]);
        }
    }
}

// ---------------- QKV GEMM (issue-early double-buffered staging) ------
__global__ __launch_bounds__(256) void qkvgemm(const __hip_bfloat16* __restrict__ A,
                                               const __hip_bfloat16* __restrict__ Bt,
                                               __hip_bfloat16* __restrict__ qb,
                                               __hip_bfloat16* __restrict__ kb,
                                               __hip_bfloat16* __restrict__ vt) {
    __shared__ __align__(1024) char lds[65536];   // [buf][A 16K | B 16K]
    int tid = threadIdx.x;
    int lane = tid & 63, w = tid >> 6;
    int wm = w >> 1, wn = w & 1;
    int row0 = blockIdx.y * 128;
    int col0 = blockIdx.x * 128;

    f32x4 acc[4][4];
#pragma unroll
    for (int i = 0; i < 4; ++i)
#pragma unroll
        for (int j = 0; j < 4; ++j) acc[i][j] = (f32x4){0.f, 0.f, 0.f, 0.f};

    auto stage = [&](int buf, int k0) {
        char* Ab = lds + buf * 32768;
        char* Bb = Ab + 16384;
#pragma unroll
        for (int i = 0; i < 4; ++i) {
            int p  = i * 4096 + tid * 16;
            int lg = p ^ (((p >> 7) & 7) << 4);
            int r  = lg >> 7, cb = lg & 127;
            gload16((const char*)(A  + (size_t)(row0 + r) * E_DIM + k0) + cb, Ab + i * 4096 + w * 1024);
            gload16((const char*)(Bt + (size_t)(col0 + r) * E_DIM + k0) + cb, Bb + i * 4096 + w * 1024);
        }
    };

    stage(0, 0);
    for (int kt = 0; kt < 6; ++kt) {
        __syncthreads();
        if (kt < 5) stage((kt + 1) & 1, (kt + 1) * 64);
        const char* Ab = lds + (kt & 1) * 32768;
        const char* Bb = Ab + 16384;
#pragma unroll
        for (int ks = 0; ks < 2; ++ks) {
            bf16x8 af[4], bfr[4];
#pragma unroll
            for (int mi = 0; mi < 4; ++mi) {
                int rl = wm * 64 + mi * 16 + (lane & 15);
                int lg = rl * 128 + ks * 64 + ((lane >> 4) << 4);
                int ph = lg ^ ((rl & 7) << 4);
                af[mi] = *(const bf16x8*)(Ab + ph);
            }
#pragma unroll
            for (int ni = 0; ni < 4; ++ni) {
                int rl = wn * 64 + ni * 16 + (lane & 15);
                int lg = rl * 128 + ks * 64 + ((lane >> 4) << 4);
                int ph = lg ^ ((rl & 7) << 4);
                bfr[ni] = *(const bf16x8*)(Bb + ph);
            }
#pragma unroll
            for (int mi = 0; mi < 4; ++mi)
#pragma unroll
                for (int ni = 0; ni < 4; ++ni)
                    acc[mi][ni] = __builtin_amdgcn_mfma_f32_16x16x32_bf16(
                        af[mi], bfr[ni], acc[mi][ni], 0, 0, 0);
        }
    }

#pragma unroll
    for (int mi = 0; mi < 4; ++mi) {
#pragma unroll
        for (int ni = 0; ni < 4; ++ni) {
            int gcl = col0 + wn * 64 + ni * 16 + (lane & 15);   // 0..1151
            int which = gcl / 384;
            int rem = gcl - which * 384;
            int h = rem >> 6, d = rem & 63;
            int gr0 = row0 + wm * 64 + mi * 16 + ((lane >> 4) << 2);
#pragma unroll
            for (int j = 0; j < 4; ++j) {
                int gr = gr0 + j;
                int b = gr >> 8, t = gr & 255;
                int bh = b * N_HEAD + h;
                __hip_bfloat16 v = __float2bfloat16(acc[mi][ni][j]);
                if (which == 0)      qb[(((size_t)bh << 8) + t) * 64 + d] = v;
                else if (which == 1) kb[(((size_t)bh << 8) + t) * 64 + d] = v;
                else                 vt[(((size_t)bh << 6) + d) * SEQ + t] = v;
            }
        }
    }
}

// ---------------- fused layer tail: proj+res+LN2+MLP+res+LN(next) -----------
__global__ __launch_bounds__(256) void tail_fused(const __hip_bfloat16* __restrict__ A,
                                                  const __hip_bfloat16* __restrict__ WoT,
                                                  const float* __restrict__ bo,
                                                  const __hip_bfloat16* __restrict__ WmT,
                                                  const float* __restrict__ bm,
                                                  const float* __restrict__ xin,
                                                  float* __restrict__ xout,
                                                  const float* __restrict__ g2,
                                                  const float* __restrict__ b2v,
                                                  const float* __restrict__ gn,
                                                  const float* __restrict__ bnv,
                                                  __hip_bfloat16* __restrict__ hout) {
    __shared__ __align__(1024) char lds[131072];
    char* Bbuf = lds;                       // + buf*49152
    char* Abuf = lds + 98304;               // + buf*4096
    float* xt  = (float*)(lds + 49152);
    char* h2   = lds + 106496;              // [32 rows][768B], XOR-swizzled
    int tid = threadIdx.x;
    int lane = tid & 63, w = tid >> 6;
    int row0 = blockIdx.x * 32;

    float xnew[2][6][4];
#pragma unroll
    for (int mi = 0; mi < 2; ++mi)
#pragma unroll
        for (int ni = 0; ni < 6; ++ni) {
            int gc = w * 96 + ni * 16 + (lane & 15);
            int lr0 = mi * 16 + ((lane >> 4) << 2);
#pragma unroll
            for (int j = 0; j < 4; ++j)
                xnew[mi][ni][j] = xin[(size_t)(row0 + lr0 + j) * E_DIM + gc];
        }

    f32x4 acc[2][6];
#pragma unroll
    for (int i = 0; i < 2; ++i)
#pragma unroll
        for (int j = 0; j < 6; ++j) acc[i][j] = (f32x4){0.f, 0.f, 0.f, 0.f};

    auto stageB = [&](const __hip_bfloat16* Bt, int buf, int k0) {
        char* Bb = Bbuf + buf * 49152;
#pragma unroll
        for (int i = 0; i < 12; ++i) {
            int p  = i * 4096 + tid * 16;
            int lg = p ^ (((p >> 7) & 7) << 4);
            int r  = lg >> 7, cb = lg & 127;
            gload16((const char*)(Bt + (size_t)r * E_DIM + k0) + cb, Bb + i * 4096 + w * 1024);
        }
    };
    auto stageA = [&](int buf, int k0) {
        int p  = tid * 16;
        int lg = p ^ (((p >> 7) & 7) << 4);
        int r  = lg >> 7, cb = lg & 127;
        gload16((const char*)(A + (size_t)(row0 + r) * E_DIM + k0) + cb,
                Abuf + buf * 4096 + w * 1024);
    };

    // ================= proj GEMM =================
    stageA(0, 0);
    stageB(WoT, 0, 0);
    for (int kt = 0; kt < 6; ++kt) {
        __syncthreads();
        if (kt < 5) { stageA((kt + 1) & 1, (kt + 1) * 64); stageB(WoT, (kt + 1) & 1, (kt + 1) * 64); }
        const char* Ab = Abuf + (kt & 1) * 4096;
        const char* Bb = Bbuf + (kt & 1) * 49152;
#pragma unroll
        for (int ks = 0; ks < 2; ++ks) {
            bf16x8 af[2], bfr[6];
#pragma unroll
            for (int mi = 0; mi < 2; ++mi) {
                int rl = mi * 16 + (lane & 15);
                int lg = rl * 128 + ks * 64 + ((lane >> 4) << 4);
                int ph = lg ^ ((rl & 7) << 4);
                af[mi] = *(const bf16x8*)(Ab + ph);
            }
#pragma unroll
            for (int ni = 0; ni < 6; ++ni) {
                int rl = w * 96 + ni * 16 + (lane & 15);
                int lg = rl * 128 + ks * 64 + ((lane >> 4) << 4);
                int ph = lg ^ ((rl & 7) << 4);
                bfr[ni] = *(const bf16x8*)(Bb + ph);
            }
#pragma unroll
            for (int mi = 0; mi < 2; ++mi)
#pragma unroll
                for (int ni = 0; ni < 6; ++ni)
                    acc[mi][ni] = __builtin_amdgcn_mfma_f32_16x16x32_bf16(
                        af[mi], bfr[ni], acc[mi][ni], 0, 0, 0);
        }
    }
    __syncthreads();
    stageB(WmT, 0, 0);          // prefetch Wm chunk0 under LN2

#pragma unroll
    for (int mi = 0; mi < 2; ++mi) {
#pragma unroll
        for (int ni = 0; ni < 6; ++ni) {
            int gc = w * 96 + ni * 16 + (lane & 15);
            int lr0 = mi * 16 + ((lane >> 4) << 2);
            float bv = bo[gc];
#pragma unroll
            for (int j = 0; j < 4; ++j) {
                float xn = xnew[mi][ni][j] + acc[mi][ni][j] + bv;
                xnew[mi][ni][j] = xn;
                xt[(lr0 + j) * 392 + gc] = xn;
            }
        }
    }
    __syncthreads();

#pragma unroll
    for (int r8 = 0; r8 < 8; ++r8) {
        int r = w * 8 + r8;
        float v[6];
        float s = 0.f;
#pragma unroll
        for (int c = 0; c < 6; ++c) { v[c] = xt[r * 392 + lane + 64 * c]; s += v[c]; }
#pragma unroll
        for (int off = 32; off > 0; off >>= 1) s += __shfl_xor(s, off);
        float mu = s * (1.0f / E_DIM);
        float s2 = 0.f;
#pragma unroll
        for (int c = 0; c < 6; ++c) { float d = v[c] - mu; s2 += d * d; }
#pragma unroll
        for (int off = 32; off > 0; off >>= 1) s2 += __shfl_xor(s2, off);
        float rstd = rsqrtf(s2 * (1.0f / E_DIM) + 1e-5f);
#pragma unroll
        for (int c = 0; c < 6; ++c) {
            int e = lane + 64 * c;
            unsigned short u = bfbits((v[c] - mu) * rstd * g2[e] + b2v[e]);
            int by = (2 * e) ^ ((r & 7) << 4);
            *(unsigned short*)(h2 + r * 768 + by) = u;
        }
    }

    // ================= MLP GEMM (A from h2 LDS) =================
#pragma unroll
    for (int i = 0; i < 2; ++i)
#pragma unroll
        for (int j = 0; j < 6; ++j) acc[i][j] = (f32x4){0.f, 0.f, 0.f, 0.f};

    for (int kt = 0; kt < 6; ++kt) {
        __syncthreads();
        if (kt < 5) stageB(WmT, (kt + 1) & 1, (kt + 1) * 64);
        const char* Bb = Bbuf + (kt & 1) * 49152;
#pragma unroll
        for (int ks = 0; ks < 2; ++ks) {
            bf16x8 af[2], bfr[6];
#pragma unroll
            for (int mi = 0; mi < 2; ++mi) {
                int rl = mi * 16 + (lane & 15);
                int koff = kt * 128 + ks * 64 + ((lane >> 4) << 4);
                int by = koff ^ ((rl & 7) << 4);
                af[mi] = *(const bf16x8*)(h2 + rl * 768 + by);
            }
#pragma unroll
            for (int ni = 0; ni < 6; ++ni) {
                int rl = w * 96 + ni * 16 + (lane & 15);
                int lg = rl * 128 + ks * 64 + ((lane >> 4) << 4);
                int ph = lg ^ ((rl & 7) << 4);
                bfr[ni] = *(const bf16x8*)(Bb + ph);
            }
#pragma unroll
            for (int mi = 0; mi < 2; ++mi)
#pragma unroll
                for (int ni = 0; ni < 6; ++ni)
                    acc[mi][ni] = __builtin_amdgcn_mfma_f32_16x16x32_bf16(
                        af[mi], bfr[ni], acc[mi][ni], 0, 0, 0);
        }
    }
    __syncthreads();

#pragma unroll
    for (int mi = 0; mi < 2; ++mi) {
#pragma unroll
        for (int ni = 0; ni < 6; ++ni) {
            int gc = w * 96 + ni * 16 + (lane & 15);
            int lr0 = mi * 16 + ((lane >> 4) << 2);
            float bv = bm[gc];
#pragma unroll
            for (int j = 0; j < 4; ++j) {
                float u = fmaxf(acc[mi][ni][j] + bv, 0.f);
                float xn = xnew[mi][ni][j] + u;
                xout[(size_t)(row0 + lr0 + j) * E_DIM + gc] = xn;
                xt[(lr0 + j) * 392 + gc] = xn;
            }
        }
    }
    __syncthreads();

#pragma unroll
    for (int r8 = 0; r8 < 8; ++r8) {
        int r = w * 8 + r8;
        float v[6];
        float s = 0.f;
#pragma unroll
        for (int c = 0; c < 6; ++c) { v[c] = xt[r * 392 + lane + 64 * c]; s += v[c]; }
#pragma unroll
        for (int off = 32; off > 0; off >>= 1) s += __shfl_xor(s, off);
        float mu = s * (1.0f / E_DIM);
        float s2 = 0.f;
#pragma unroll
        for (int c = 0; c < 6; ++c) { float d = v[c] - mu; s2 += d * d; }
#pragma unroll
        for (int off = 32; off > 0; off >>= 1) s2 += __shfl_xor(s2, off);
        float rstd = rsqrtf(s2 * (1.0f / E_DIM) + 1e-5f);
        __hip_bfloat16* hr = hout + (size_t)(row0 + r) * E_DIM;
#pragma unroll
        for (int c = 0; c < 6; ++c) {
            int e = lane + 64 * c;
            hr[e] = __float2bfloat16((v[c] - mu) * rstd * gn[e] + bnv[e]);
        }
    }
}

// ---------------- LM-head GEMM: bx-major + within-XCD column-chunking ----------
// Per XCD (1572 blocks): 12 chunks of <=33 col-tiles x 4 row panels. A chunk's
// B-stripe (3.1 MB) is L2-resident and its 132 blocks fit the ~160-block
// residency window, so B crosses L3->L2 once per XCD (not 4x). Within a chunk,
// bx varies fastest at fixed panel (write-coalescing locality preserved).
__global__ __launch_bounds__(256) void mgemm_lm(const __hip_bfloat16* __restrict__ A,
                                                const __hip_bfloat16* __restrict__ Bt,
                                                const float* __restrict__ bias,
                                                float* __restrict__ C) {
    __shared__ __align__(1024) char lds[32768];
    char* Ar = lds;
    char* Br = lds + 16384;
    int tid = threadIdx.x;
    int lane = tid & 63, w = tid >> 6;
    int wm = w >> 1, wn = w & 1;

    // bijective: wg -> (xcd, k) -> (chunk, panel, col)
    int wg  = blockIdx.y * 393 + blockIdx.x;
    int xcd = wg & 7;
    int k   = wg >> 3;                         // 0..1571
    int c, r, wc;
    if (k < 1452) { c = k / 132; r = k - c * 132; wc = 33; }
    else          { c = 11;      r = k - 1452;    wc = 30; }
    int byl = r / wc, bxl = r - byl * wc;
    int bx  = c * 33 + bxl;                    // 0..392
    int by  = xcd * 4 + byl;                   // 0..31
    int row0 = by * 128;
    int col0 = bx * 128;

    f32x4 acc[4][4];
#pragma unroll
    for (int i = 0; i < 4; ++i)
#pragma unroll
        for (int j = 0; j < 4; ++j) acc[i][j] = (f32x4){0.f, 0.f, 0.f, 0.f};

    for (int k0 = 0; k0 < E_DIM; k0 += 64) {
        __syncthreads();
#pragma unroll
        for (int i = 0; i < 4; ++i) {
            int p  = i * 4096 + tid * 16;
            int lg = p ^ (((p >> 7) & 7) << 4);
            int rr = lg >> 7, cb = lg & 127;
            gload16((const char*)(A  + (size_t)(row0 + rr) * E_DIM + k0) + cb, Ar + i * 4096 + w * 1024);
            gload16((const char*)(Bt + (size_t)(col0 + rr) * E_DIM + k0) + cb, Br + i * 4096 + w * 1024);
        }
        __syncthreads();
#pragma unroll
        for (int ks = 0; ks < 2; ++ks) {
            bf16x8 af[4], bfr[4];
#pragma unroll
            for (int mi = 0; mi < 4; ++mi) {
                int rl = wm * 64 + mi * 16 + (lane & 15);
                int lg = rl * 128 + ks * 64 + ((lane >> 4) << 4);
                int ph = lg ^ ((rl & 7) << 4);
                af[mi] = *(const bf16x8*)(Ar + ph);
            }
#pragma unroll
            for (int ni = 0; ni < 4; ++ni) {
                int rl = wn * 64 + ni * 16 + (lane & 15);
                int lg = rl * 128 + ks * 64 + ((lane >> 4) << 4);
                int ph = lg ^ ((rl & 7) << 4);
                bfr[ni] = *(const bf16x8*)(Br + ph);
            }
#pragma unroll
            for (int mi = 0; mi < 4; ++mi)
#pragma unroll
                for (int ni = 0; ni < 4; ++ni)
                    acc[mi][ni] = __builtin_amdgcn_mfma_f32_16x16x32_bf16(
                        af[mi], bfr[ni], acc[mi][ni], 0, 0, 0);
        }
    }

#pragma unroll
    for (int mi = 0; mi < 4; ++mi) {
#pragma unroll
        for (int ni = 0; ni < 4; ++ni) {
            int gr = row0 + wm * 64 + mi * 16 + ((lane >> 4) << 2);
            int gc = col0 + wn * 64 + ni * 16 + (lane & 15);
            if (gc < VOCAB) {
                float bv = bias[gc];
#pragma unroll
                for (int j = 0; j < 4; ++j)
                    C[(size_t)(gr + j) * VOCAB + gc] = acc[mi][ni][j] + bv;
            }
        }
    }
}

// ---------------- fused MFMA attention (72 KB LDS, P aliases K) -------
#define ATT_K 0
#define ATT_V 32768
#define ATT_Q 65536

__global__ __launch_bounds__(256) void attn_fused(const __hip_bfloat16* __restrict__ qb,
                                                  const __hip_bfloat16* __restrict__ kb,
                                                  const __hip_bfloat16* __restrict__ vt,
                                                  __hip_bfloat16* __restrict__ o) {
    __shared__ __align__(1024) char lds[73728];
    int tid = threadIdx.x;
    int lane = tid & 63, w = tid >> 6;
    int bh = blockIdx.x;
    int mq = blockIdx.y;
    int b = bh / N_HEAD, h = bh - b * N_HEAD;

    const char* kg = (const char*)(kb + (size_t)bh * SEQ * 64);
#pragma unroll
    for (int i = 0; i < 8; ++i) {
        int p = i * 4096 + tid * 16;
        int lg = p ^ (((p >> 7) & 7) << 4);
        gload16(kg + lg, lds + ATT_K + p);
    }
    const char* vg = (const char*)(vt + (size_t)bh * 64 * SEQ);
#pragma unroll
    for (int i = 0; i < 8; ++i) {
        int p = i * 4096 + tid * 16;
        int lg = p ^ (((p >> 9) & 7) << 4);
        gload16(vg + lg, lds + ATT_V + p);
    }
    const char* qg = (const char*)(qb + ((size_t)bh * SEQ + mq * 64) * 64);
#pragma unroll
    for (int i = 0; i < 2; ++i) {
        int p = i * 4096 + tid * 16;
        int lg = p ^ (((p >> 7) & 7) << 4);
        gload16(qg + lg, lds + ATT_Q + p);
    }
    __syncthreads();

    int q0 = w * 16;
    int qg0 = mq * 64 + q0;

    f32x4 acc[16];
#pragma unroll
    for (int n = 0; n < 16; ++n) acc[n] = (f32x4){0.f, 0.f, 0.f, 0.f};
#pragma unroll
    for (int ks = 0; ks < 2; ++ks) {
        int rq = q0 + (lane & 15);
        int byq = (ks * 64 + ((lane >> 4) << 4)) ^ ((rq & 7) << 4);
        bf16x8 aq = *(const bf16x8*)(lds + ATT_Q + rq * 128 + byq);
#pragma unroll
        for (int n = 0; n < 16; ++n) {
            int rk = n * 16 + (lane & 15);
            int byk = (ks * 64 + ((lane >> 4) << 4)) ^ ((rk & 7) << 4);
            bf16x8 bk = *(const bf16x8*)(lds + ATT_K + rk * 128 + byk);
            acc[n] = __builtin_amdgcn_mfma_f32_16x16x32_bf16(aq, bk, acc[n], 0, 0, 0);
        }
    }
    __syncthreads();   // all K reads done; P may overwrite K region

    char* pbase = lds + ATT_K + w * 8192;   // per-wave [16][256] bf16
#pragma unroll
    for (int j = 0; j < 4; ++j) {
        int rql = ((lane >> 4) << 2) + j;
        int rg = qg0 + rql;
        float s[16];
        float m = -INFINITY;
#pragma unroll
        for (int n = 0; n < 16; ++n) {
            int cg = n * 16 + (lane & 15);
            float v = (cg <= rg) ? acc[n][j] * 0.125f : -INFINITY;
            s[n] = v;
            m = fmaxf(m, v);
        }
#pragma unroll
        for (int off = 1; off < 16; off <<= 1) m = fmaxf(m, __shfl_xor(m, off));
        float sum = 0.f;
#pragma unroll
        for (int n = 0; n < 16; ++n) { s[n] = __expf(s[n] - m); sum += s[n]; }
#pragma unroll
        for (int off = 1; off < 16; off <<= 1) sum += __shfl_xor(sum, off);
        float inv = 1.0f / sum;
#pragma unroll
        for (int n = 0; n < 16; ++n) {
            int cg = n * 16 + (lane & 15);
            int by = (cg * 2) ^ ((rql & 7) << 4);
            *(__hip_bfloat16*)(pbase + rql * 512 + by) = __float2bfloat16(s[n] * inv);
        }
    }

    f32x4 oacc[4];
#pragma unroll
    for (int nf = 0; nf < 4; ++nf) oacc[nf] = (f32x4){0.f, 0.f, 0.f, 0.f};
#pragma unroll
    for (int ks = 0; ks < 8; ++ks) {
        int rp = lane & 15;
        int byp = (ks * 64 + ((lane >> 4) << 4)) ^ ((rp & 7) << 4);
        bf16x8 ap = *(const bf16x8*)(pbase + rp * 512 + byp);
#pragma unroll
        for (int nf = 0; nf < 4; ++nf) {
            int rv = nf * 16 + (lane & 15);
            int byv = (ks * 64 + ((lane >> 4) << 4)) ^ ((rv & 7) << 4);
            bf16x8 bv = *(const bf16x8*)(lds + ATT_V + rv * 512 + byv);
            oacc[nf] = __builtin_amdgcn_mfma_f32_16x16x32_bf16(ap, bv, oacc[nf], 0, 0, 0);
        }
    }

#pragma unroll
    for (int nf = 0; nf < 4; ++nf) {
#pragma unroll
        for (int j = 0; j < 4; ++j) {
            int t = mq * 64 + q0 + ((lane >> 4) << 2) + j;
            int d = nf * 16 + (lane & 15);
            o[(size_t)(b * SEQ + t) * E_DIM + h * 64 + d] = __float2bfloat16(oacc[nf][j]);
        }
    }
}

extern "C" void kernel_launch(void* const* d_in, const int* in_sizes, int n_in,
                              void* d_out, int out_size, void* d_ws, size_t ws_size,
                              hipStream_t stream) {
    const int*   idx  = (const int*)d_in[0];
    const float* tok  = (const float*)d_in[1];
    const float* pos  = (const float*)d_in[2];
    const float* Wq   = (const float*)d_in[3];
    const float* Wk   = (const float*)d_in[4];
    const float* Wv   = (const float*)d_in[5];
    const float* Wo   = (const float*)d_in[6];
    const float* bo   = (const float*)d_in[7];
    const float* ln1g = (const float*)d_in[8];
    const float* ln1b = (const float*)d_in[9];
    const float* ln2g = (const float*)d_in[10];
    const float* ln2b = (const float*)d_in[11];
    const float* Wm   = (const float*)d_in[12];
    const float* bm   = (const float*)d_in[13];
    const float* lnfg = (const float*)d_in[14];
    const float* lnfb = (const float*)d_in[15];
    const float* Wlm  = (const float*)d_in[16];
    const float* blm  = (const float*)d_in[17];
    float* out = (float*)d_out;

    float*           x    = (float*)d_ws;                         // [4096][384] f32
    __hip_bfloat16*  hb   = (__hip_bfloat16*)(x + (size_t)NTOK * E_DIM);
    __hip_bfloat16*  WtL  = hb + (size_t)NTOK * E_DIM;
    __hip_bfloat16*  WtLM = WtL + (size_t)NLAYER * 1920 * E_DIM;  // [50304][384]
    __hip_bfloat16*  qbv  = WtLM + (size_t)VPAD * E_DIM;
    __hip_bfloat16*  kbv  = qbv + (size_t)NBH * SEQ * 64;
    __hip_bfloat16*  vtb  = kbv + (size_t)NBH * SEQ * 64;

    prep_kernel<<<1080 + 786 * 6 + NTOK / 4, 256, 0, stream>>>(
        Wq, Wk, Wv, Wo, Wm, Wlm, WtL, WtLM, idx, tok, pos, ln1g, ln1b, x, hb);

    for (int l = 0; l < NLAYER; ++l) {
        const __hip_bfloat16* wl = WtL + (size_t)l * 1920 * E_DIM;
        qkvgemm<<<dim3(QKV_N / 128, NTOK / 128), 256, 0, stream>>>(hb, wl, qbv, kbv, vtb);
        attn_fused<<<dim3(NBH, 4), 256, 0, stream>>>(qbv, kbv, vtb, hb);
        const float* ng = (l == NLAYER - 1) ? lnfg : ln1g + (l + 1) * E_DIM;
        const float* nb = (l == NLAYER - 1) ? lnfb : ln1b + (l + 1) * E_DIM;
        tail_fused<<<NTOK / 32, 256, 0, stream>>>(hb, wl + (size_t)1152 * E_DIM,
                                                  bo + l * E_DIM,
                                                  wl + (size_t)1536 * E_DIM,
                                                  bm + l * E_DIM,
                                                  x, x,
                                                  ln2g + l * E_DIM, ln2b + l * E_DIM,
                                                  ng, nb, hb);
    }

    mgemm_lm<<<dim3(VPAD / 128, NTOK / 128), 256, 0, stream>>>(hb, WtLM, blm, out);
}

// Round 12
// 737.772 us; speedup vs baseline: 1.0198x; 1.0198x over previous
//
#include <hip/hip_runtime.h>
#include <hip/hip_bf16.h>
#include <math.h>

#define E_DIM 384
#define N_HEAD 6
#define HEAD_SZ 64
#define SEQ 256
#define BATCH 16
#define NTOK 4096
#define NLAYER 6
#define VOCAB 50257
#define VPAD2 50432         // 197*256 (LM-head N padding, tile N=256)
#define LMTILES 788         // 50432/64 (prep transpose tiles per K-row)
#define QKV_N 1152          // 3*E
#define NBH 96              // BATCH*N_HEAD

typedef __attribute__((ext_vector_type(8))) short bf16x8;
typedef __attribute__((ext_vector_type(4))) float f32x4;

__device__ __forceinline__ void gload16(const void* g, void* l) {
    __builtin_amdgcn_global_load_lds((const __attribute__((address_space(1))) char*)g,
                                     (__attribute__((address_space(3))) char*)l, 16, 0, 0);
}

__device__ __forceinline__ unsigned short bfbits(float x) {
    __hip_bfloat16 h = __float2bfloat16(x);
    return *reinterpret_cast<unsigned short*>(&h);
}

// ---------------- prep: weight transposes + embedding + LN1, one dispatch ------
__device__ __forceinline__ void tconv_tile(const float* __restrict__ src,
                                           __hip_bfloat16* __restrict__ dst,
                                           int K, int N, int n0, int k0) {
    __shared__ float tbuf[64][65];
    int c = threadIdx.x & 63, r4 = threadIdx.x >> 6;
#pragma unroll
    for (int i = 0; i < 16; ++i) {
        int r = r4 * 16 + i;
        float v = 0.f;
        if (n0 + c < N) v = src[(size_t)(k0 + r) * N + n0 + c];
        tbuf[r][c] = v;
    }
    __syncthreads();
#pragma unroll
    for (int i = 0; i < 16; ++i) {
        int rn = r4 * 16 + i;
        dst[(size_t)(n0 + rn) * K + k0 + c] = __float2bfloat16(tbuf[c][rn]);
    }
}

__global__ __launch_bounds__(256) void prep_kernel(const float* __restrict__ Wq,
                                                   const float* __restrict__ Wk,
                                                   const float* __restrict__ Wv,
                                                   const float* __restrict__ Wo,
                                                   const float* __restrict__ Wm,
                                                   const float* __restrict__ Wlm,
                                                   __hip_bfloat16* __restrict__ WtL,
                                                   __hip_bfloat16* __restrict__ WtLM,
                                                   const int* __restrict__ idx,
                                                   const float* __restrict__ tok,
                                                   const float* __restrict__ pos,
                                                   const float* __restrict__ g,
                                                   const float* __restrict__ b,
                                                   float* __restrict__ x,
                                                   __hip_bfloat16* __restrict__ h) {
    int bid = blockIdx.x;
    if (bid < 1080) {              // per-layer weights: 30 z-slices x 36 tiles
        int z = bid / 36, rem = bid - z * 36;
        int bx = rem % 6, by = rem / 6;
        int l = z / 5, t = z - l * 5;
        const float* src;
        int dstoff;
        switch (t) {
            case 0: src = Wq; dstoff = 0;    break;
            case 1: src = Wk; dstoff = 384;  break;
            case 2: src = Wv; dstoff = 768;  break;
            case 3: src = Wo; dstoff = 1152; break;
            default: src = Wm; dstoff = 1536;
        }
        src += (size_t)l * E_DIM * E_DIM;
        __hip_bfloat16* dst = WtL + ((size_t)l * 1920 + dstoff) * E_DIM;
        tconv_tile(src, dst, E_DIM, E_DIM, bx * 64, by * 64);
    } else if (bid < 1080 + LMTILES * 6) {   // LM head transpose (pads to VPAD2)
        int b2 = bid - 1080;
        int bx = b2 % LMTILES, by = b2 / LMTILES;
        tconv_tile(Wlm, WtLM, E_DIM, VOCAB, bx * 64, by * 64);
    } else {                       // embedding + LN1: 1024 blocks x 4 rows
        int rb = bid - (1080 + LMTILES * 6);
        int lane = threadIdx.x & 63;
        int w = threadIdx.x >> 6;
        int row = rb * 4 + w;
        int t = row & (SEQ - 1);
        const float* tr = tok + (size_t)idx[row] * E_DIM;
        const float* pr = pos + (size_t)t * E_DIM;
        float* xr = x + (size_t)row * E_DIM;
        float v[6];
        float s = 0.f;
#pragma unroll
        for (int c = 0; c < 6; ++c) {
            int e = lane + 64 * c;
            v[c] = tr[e] + pr[e];
            xr[e] = v[c];
            s += v[c];
        }
#pragma unroll
        for (int off = 32; off > 0; off >>= 1) s += __shfl_xor(s, off);
        float mu = s * (1.0f / E_DIM);
        float s2 = 0.f;
#pragma unroll
        for (int c = 0; c < 6; ++c) { float d = v[c] - mu; s2 += d * d; }
#pragma unroll
        for (int off = 32; off > 0; off >>= 1) s2 += __shfl_xor(s2, off);
        float rstd = rsqrtf(s2 * (1.0f / E_DIM) + 1e-5f);
        __hip_bfloat16* hr = h + (size_t)row * E_DIM;
#pragma unroll
        for (int c = 0; c < 6; ++c) {
            int e = lane + 64 * c;
            hr[e] = __float2bfloat16((v[c] - mu) * rstd * g[e] + b[e]);
        }
    }
}

// ---------------- QKV GEMM (issue-early double-buffered staging) ------
__global__ __launch_bounds__(256) void qkvgemm(const __hip_bfloat16* __restrict__ A,
                                               const __hip_bfloat16* __restrict__ Bt,
                                               __hip_bfloat16* __restrict__ qb,
                                               __hip_bfloat16* __restrict__ kb,
                                               __hip_bfloat16* __restrict__ vt) {
    __shared__ __align__(1024) char lds[65536];   // [buf][A 16K | B 16K]
    int tid = threadIdx.x;
    int lane = tid & 63, w = tid >> 6;
    int wm = w >> 1, wn = w & 1;
    int row0 = blockIdx.y * 128;
    int col0 = blockIdx.x * 128;

    f32x4 acc[4][4];
#pragma unroll
    for (int i = 0; i < 4; ++i)
#pragma unroll
        for (int j = 0; j < 4; ++j) acc[i][j] = (f32x4){0.f, 0.f, 0.f, 0.f};

    auto stage = [&](int buf, int k0) {
        char* Ab = lds + buf * 32768;
        char* Bb = Ab + 16384;
#pragma unroll
        for (int i = 0; i < 4; ++i) {
            int p  = i * 4096 + tid * 16;
            int lg = p ^ (((p >> 7) & 7) << 4);
            int r  = lg >> 7, cb = lg & 127;
            gload16((const char*)(A  + (size_t)(row0 + r) * E_DIM + k0) + cb, Ab + i * 4096 + w * 1024);
            gload16((const char*)(Bt + (size_t)(col0 + r) * E_DIM + k0) + cb, Bb + i * 4096 + w * 1024);
        }
    };

    stage(0, 0);
    for (int kt = 0; kt < 6; ++kt) {
        __syncthreads();
        if (kt < 5) stage((kt + 1) & 1, (kt + 1) * 64);
        const char* Ab = lds + (kt & 1) * 32768;
        const char* Bb = Ab + 16384;
#pragma unroll
        for (int ks = 0; ks < 2; ++ks) {
            bf16x8 af[4], bfr[4];
#pragma unroll
            for (int mi = 0; mi < 4; ++mi) {
                int rl = wm * 64 + mi * 16 + (lane & 15);
                int lg = rl * 128 + ks * 64 + ((lane >> 4) << 4);
                int ph = lg ^ ((rl & 7) << 4);
                af[mi] = *(const bf16x8*)(Ab + ph);
            }
#pragma unroll
            for (int ni = 0; ni < 4; ++ni) {
                int rl = wn * 64 + ni * 16 + (lane & 15);
                int lg = rl * 128 + ks * 64 + ((lane >> 4) << 4);
                int ph = lg ^ ((rl & 7) << 4);
                bfr[ni] = *(const bf16x8*)(Bb + ph);
            }
#pragma unroll
            for (int mi = 0; mi < 4; ++mi)
#pragma unroll
                for (int ni = 0; ni < 4; ++ni)
                    acc[mi][ni] = __builtin_amdgcn_mfma_f32_16x16x32_bf16(
                        af[mi], bfr[ni], acc[mi][ni], 0, 0, 0);
        }
    }

#pragma unroll
    for (int mi = 0; mi < 4; ++mi) {
#pragma unroll
        for (int ni = 0; ni < 4; ++ni) {
            int gcl = col0 + wn * 64 + ni * 16 + (lane & 15);   // 0..1151
            int which = gcl / 384;
            int rem = gcl - which * 384;
            int h = rem >> 6, d = rem & 63;
            int gr0 = row0 + wm * 64 + mi * 16 + ((lane >> 4) << 2);
#pragma unroll
            for (int j = 0; j < 4; ++j) {
                int gr = gr0 + j;
                int b = gr >> 8, t = gr & 255;
                int bh = b * N_HEAD + h;
                __hip_bfloat16 v = __float2bfloat16(acc[mi][ni][j]);
                if (which == 0)      qb[(((size_t)bh << 8) + t) * 64 + d] = v;
                else if (which == 1) kb[(((size_t)bh << 8) + t) * 64 + d] = v;
                else                 vt[(((size_t)bh << 6) + d) * SEQ + t] = v;
            }
        }
    }
}

// ---------------- fused layer tail: proj+res+LN2+MLP+res+LN(next) -----------
__global__ __launch_bounds__(256) void tail_fused(const __hip_bfloat16* __restrict__ A,
                                                  const __hip_bfloat16* __restrict__ WoT,
                                                  const float* __restrict__ bo,
                                                  const __hip_bfloat16* __restrict__ WmT,
                                                  const float* __restrict__ bm,
                                                  const float* __restrict__ xin,
                                                  float* __restrict__ xout,
                                                  const float* __restrict__ g2,
                                                  const float* __restrict__ b2v,
                                                  const float* __restrict__ gn,
                                                  const float* __restrict__ bnv,
                                                  __hip_bfloat16* __restrict__ hout) {
    __shared__ __align__(1024) char lds[131072];
    char* Bbuf = lds;                       // + buf*49152
    char* Abuf = lds + 98304;               // + buf*4096
    float* xt  = (float*)(lds + 49152);
    char* h2   = lds + 106496;              // [32 rows][768B], XOR-swizzled
    int tid = threadIdx.x;
    int lane = tid & 63, w = tid >> 6;
    int row0 = blockIdx.x * 32;

    float xnew[2][6][4];
#pragma unroll
    for (int mi = 0; mi < 2; ++mi)
#pragma unroll
        for (int ni = 0; ni < 6; ++ni) {
            int gc = w * 96 + ni * 16 + (lane & 15);
            int lr0 = mi * 16 + ((lane >> 4) << 2);
#pragma unroll
            for (int j = 0; j < 4; ++j)
                xnew[mi][ni][j] = xin[(size_t)(row0 + lr0 + j) * E_DIM + gc];
        }

    f32x4 acc[2][6];
#pragma unroll
    for (int i = 0; i < 2; ++i)
#pragma unroll
        for (int j = 0; j < 6; ++j) acc[i][j] = (f32x4){0.f, 0.f, 0.f, 0.f};

    auto stageB = [&](const __hip_bfloat16* Bt, int buf, int k0) {
        char* Bb = Bbuf + buf * 49152;
#pragma unroll
        for (int i = 0; i < 12; ++i) {
            int p  = i * 4096 + tid * 16;
            int lg = p ^ (((p >> 7) & 7) << 4);
            int r  = lg >> 7, cb = lg & 127;
            gload16((const char*)(Bt + (size_t)r * E_DIM + k0) + cb, Bb + i * 4096 + w * 1024);
        }
    };
    auto stageA = [&](int buf, int k0) {
        int p  = tid * 16;
        int lg = p ^ (((p >> 7) & 7) << 4);
        int r  = lg >> 7, cb = lg & 127;
        gload16((const char*)(A + (size_t)(row0 + r) * E_DIM + k0) + cb,
                Abuf + buf * 4096 + w * 1024);
    };

    // ================= proj GEMM =================
    stageA(0, 0);
    stageB(WoT, 0, 0);
    for (int kt = 0; kt < 6; ++kt) {
        __syncthreads();
        if (kt < 5) { stageA((kt + 1) & 1, (kt + 1) * 64); stageB(WoT, (kt + 1) & 1, (kt + 1) * 64); }
        const char* Ab = Abuf + (kt & 1) * 4096;
        const char* Bb = Bbuf + (kt & 1) * 49152;
#pragma unroll
        for (int ks = 0; ks < 2; ++ks) {
            bf16x8 af[2], bfr[6];
#pragma unroll
            for (int mi = 0; mi < 2; ++mi) {
                int rl = mi * 16 + (lane & 15);
                int lg = rl * 128 + ks * 64 + ((lane >> 4) << 4);
                int ph = lg ^ ((rl & 7) << 4);
                af[mi] = *(const bf16x8*)(Ab + ph);
            }
#pragma unroll
            for (int ni = 0; ni < 6; ++ni) {
                int rl = w * 96 + ni * 16 + (lane & 15);
                int lg = rl * 128 + ks * 64 + ((lane >> 4) << 4);
                int ph = lg ^ ((rl & 7) << 4);
                bfr[ni] = *(const bf16x8*)(Bb + ph);
            }
#pragma unroll
            for (int mi = 0; mi < 2; ++mi)
#pragma unroll
                for (int ni = 0; ni < 6; ++ni)
                    acc[mi][ni] = __builtin_amdgcn_mfma_f32_16x16x32_bf16(
                        af[mi], bfr[ni], acc[mi][ni], 0, 0, 0);
        }
    }
    __syncthreads();
    stageB(WmT, 0, 0);          // prefetch Wm chunk0 under LN2

#pragma unroll
    for (int mi = 0; mi < 2; ++mi) {
#pragma unroll
        for (int ni = 0; ni < 6; ++ni) {
            int gc = w * 96 + ni * 16 + (lane & 15);
            int lr0 = mi * 16 + ((lane >> 4) << 2);
            float bv = bo[gc];
#pragma unroll
            for (int j = 0; j < 4; ++j) {
                float xn = xnew[mi][ni][j] + acc[mi][ni][j] + bv;
                xnew[mi][ni][j] = xn;
                xt[(lr0 + j) * 392 + gc] = xn;
            }
        }
    }
    __syncthreads();

#pragma unroll
    for (int r8 = 0; r8 < 8; ++r8) {
        int r = w * 8 + r8;
        float v[6];
        float s = 0.f;
#pragma unroll
        for (int c = 0; c < 6; ++c) { v[c] = xt[r * 392 + lane + 64 * c]; s += v[c]; }
#pragma unroll
        for (int off = 32; off > 0; off >>= 1) s += __shfl_xor(s, off);
        float mu = s * (1.0f / E_DIM);
        float s2 = 0.f;
#pragma unroll
        for (int c = 0; c < 6; ++c) { float d = v[c] - mu; s2 += d * d; }
#pragma unroll
        for (int off = 32; off > 0; off >>= 1) s2 += __shfl_xor(s2, off);
        float rstd = rsqrtf(s2 * (1.0f / E_DIM) + 1e-5f);
#pragma unroll
        for (int c = 0; c < 6; ++c) {
            int e = lane + 64 * c;
            unsigned short u = bfbits((v[c] - mu) * rstd * g2[e] + b2v[e]);
            int by = (2 * e) ^ ((r & 7) << 4);
            *(unsigned short*)(h2 + r * 768 + by) = u;
        }
    }

    // ================= MLP GEMM (A from h2 LDS) =================
#pragma unroll
    for (int i = 0; i < 2; ++i)
#pragma unroll
        for (int j = 0; j < 6; ++j) acc[i][j] = (f32x4){0.f, 0.f, 0.f, 0.f};

    for (int kt = 0; kt < 6; ++kt) {
        __syncthreads();
        if (kt < 5) stageB(WmT, (kt + 1) & 1, (kt + 1) * 64);
        const char* Bb = Bbuf + (kt & 1) * 49152;
#pragma unroll
        for (int ks = 0; ks < 2; ++ks) {
            bf16x8 af[2], bfr[6];
#pragma unroll
            for (int mi = 0; mi < 2; ++mi) {
                int rl = mi * 16 + (lane & 15);
                int koff = kt * 128 + ks * 64 + ((lane >> 4) << 4);
                int by = koff ^ ((rl & 7) << 4);
                af[mi] = *(const bf16x8*)(h2 + rl * 768 + by);
            }
#pragma unroll
            for (int ni = 0; ni < 6; ++ni) {
                int rl = w * 96 + ni * 16 + (lane & 15);
                int lg = rl * 128 + ks * 64 + ((lane >> 4) << 4);
                int ph = lg ^ ((rl & 7) << 4);
                bfr[ni] = *(const bf16x8*)(Bb + ph);
            }
#pragma unroll
            for (int mi = 0; mi < 2; ++mi)
#pragma unroll
                for (int ni = 0; ni < 6; ++ni)
                    acc[mi][ni] = __builtin_amdgcn_mfma_f32_16x16x32_bf16(
                        af[mi], bfr[ni], acc[mi][ni], 0, 0, 0);
        }
    }
    __syncthreads();

#pragma unroll
    for (int mi = 0; mi < 2; ++mi) {
#pragma unroll
        for (int ni = 0; ni < 6; ++ni) {
            int gc = w * 96 + ni * 16 + (lane & 15);
            int lr0 = mi * 16 + ((lane >> 4) << 2);
            float bv = bm[gc];
#pragma unroll
            for (int j = 0; j < 4; ++j) {
                float u = fmaxf(acc[mi][ni][j] + bv, 0.f);
                float xn = xnew[mi][ni][j] + u;
                xout[(size_t)(row0 + lr0 + j) * E_DIM + gc] = xn;
                xt[(lr0 + j) * 392 + gc] = xn;
            }
        }
    }
    __syncthreads();

#pragma unroll
    for (int r8 = 0; r8 < 8; ++r8) {
        int r = w * 8 + r8;
        float v[6];
        float s = 0.f;
#pragma unroll
        for (int c = 0; c < 6; ++c) { v[c] = xt[r * 392 + lane + 64 * c]; s += v[c]; }
#pragma unroll
        for (int off = 32; off > 0; off >>= 1) s += __shfl_xor(s, off);
        float mu = s * (1.0f / E_DIM);
        float s2 = 0.f;
#pragma unroll
        for (int c = 0; c < 6; ++c) { float d = v[c] - mu; s2 += d * d; }
#pragma unroll
        for (int off = 32; off > 0; off >>= 1) s2 += __shfl_xor(s2, off);
        float rstd = rsqrtf(s2 * (1.0f / E_DIM) + 1e-5f);
        __hip_bfloat16* hr = hout + (size_t)(row0 + r) * E_DIM;
#pragma unroll
        for (int c = 0; c < 6; ++c) {
            int e = lane + 64 * c;
            hr[e] = __float2bfloat16((v[c] - mu) * rstd * gn[e] + bnv[e]);
        }
    }
}

// ---------------- LM-head GEMM: 128x256 tile (wide-N for write granularity) ----
// bx-major XCD walk (write locality, R10-proven). Per C-row the block now
// writes 1KB contiguous (vs 512B) -> fewer partial-line seams (196 vs 393 per
// row), longer HBM bursts; A re-fetch halves. Same BK=64 2-barrier structure,
// same per-wave 64x64 acc shape; 8 waves (2 row x 4 col), 48KB LDS.
__global__ __launch_bounds__(512) void mgemm_lm(const __hip_bfloat16* __restrict__ A,
                                                const __hip_bfloat16* __restrict__ Bt,
                                                const float* __restrict__ bias,
                                                float* __restrict__ C) {
    __shared__ __align__(1024) char lds[49152];   // A 16K | B 32K
    char* Ar = lds;
    char* Br = lds + 16384;
    int tid = threadIdx.x;
    int lane = tid & 63, w = tid >> 6;
    int wm = w >> 2, wn = w & 3;                  // 2x4 waves -> 64x64 each

    // bijective XCD swizzle: grid 197x32 = 6304 = 8*788, bx-major within XCD
    int wg  = blockIdx.y * 197 + blockIdx.x;
    int swz = (wg & 7) * 788 + (wg >> 3);
    int bx  = swz % 197, by = swz / 197;
    int row0 = by * 128;
    int col0 = bx * 256;

    f32x4 acc[4][4];
#pragma unroll
    for (int i = 0; i < 4; ++i)
#pragma unroll
        for (int j = 0; j < 4; ++j) acc[i][j] = (f32x4){0.f, 0.f, 0.f, 0.f};

    for (int k0 = 0; k0 < E_DIM; k0 += 64) {
        __syncthreads();
#pragma unroll
        for (int i = 0; i < 2; ++i) {    // A: 128 rows x 128B = 16KB
            int p  = i * 8192 + tid * 16;
            int lg = p ^ (((p >> 7) & 7) << 4);
            int r  = lg >> 7, cb = lg & 127;
            gload16((const char*)(A + (size_t)(row0 + r) * E_DIM + k0) + cb,
                    Ar + i * 8192 + w * 1024);
        }
#pragma unroll
        for (int i = 0; i < 4; ++i) {    // B: 256 rows x 128B = 32KB
            int p  = i * 8192 + tid * 16;
            int lg = p ^ (((p >> 7) & 7) << 4);
            int r  = lg >> 7, cb = lg & 127;
            gload16((const char*)(Bt + (size_t)(col0 + r) * E_DIM + k0) + cb,
                    Br + i * 8192 + w * 1024);
        }
        __syncthreads();
#pragma unroll
        for (int ks = 0; ks < 2; ++ks) {
            bf16x8 af[4], bfr[4];
#pragma unroll
            for (int mi = 0; mi < 4; ++mi) {
                int rl = wm * 64 + mi * 16 + (lane & 15);
                int lg = rl * 128 + ks * 64 + ((lane >> 4) << 4);
                int ph = lg ^ ((rl & 7) << 4);
                af[mi] = *(const bf16x8*)(Ar + ph);
            }
#pragma unroll
            for (int ni = 0; ni < 4; ++ni) {
                int rl = wn * 64 + ni * 16 + (lane & 15);
                int lg = rl * 128 + ks * 64 + ((lane >> 4) << 4);
                int ph = lg ^ ((rl & 7) << 4);
                bfr[ni] = *(const bf16x8*)(Br + ph);
            }
#pragma unroll
            for (int mi = 0; mi < 4; ++mi)
#pragma unroll
                for (int ni = 0; ni < 4; ++ni)
                    acc[mi][ni] = __builtin_amdgcn_mfma_f32_16x16x32_bf16(
                        af[mi], bfr[ni], acc[mi][ni], 0, 0, 0);
        }
    }

#pragma unroll
    for (int mi = 0; mi < 4; ++mi) {
#pragma unroll
        for (int ni = 0; ni < 4; ++ni) {
            int gr = row0 + wm * 64 + mi * 16 + ((lane >> 4) << 2);
            int gc = col0 + wn * 64 + ni * 16 + (lane & 15);
            if (gc < VOCAB) {
                float bv = bias[gc];
#pragma unroll
                for (int j = 0; j < 4; ++j)
                    C[(size_t)(gr + j) * VOCAB + gc] = acc[mi][ni][j] + bv;
            }
        }
    }
}

// ---------------- fused MFMA attention (72 KB LDS, P aliases K) -------
#define ATT_K 0
#define ATT_V 32768
#define ATT_Q 65536

__global__ __launch_bounds__(256) void attn_fused(const __hip_bfloat16* __restrict__ qb,
                                                  const __hip_bfloat16* __restrict__ kb,
                                                  const __hip_bfloat16* __restrict__ vt,
                                                  __hip_bfloat16* __restrict__ o) {
    __shared__ __align__(1024) char lds[73728];
    int tid = threadIdx.x;
    int lane = tid & 63, w = tid >> 6;
    int bh = blockIdx.x;
    int mq = blockIdx.y;
    int b = bh / N_HEAD, h = bh - b * N_HEAD;

    const char* kg = (const char*)(kb + (size_t)bh * SEQ * 64);
#pragma unroll
    for (int i = 0; i < 8; ++i) {
        int p = i * 4096 + tid * 16;
        int lg = p ^ (((p >> 7) & 7) << 4);
        gload16(kg + lg, lds + ATT_K + p);
    }
    const char* vg = (const char*)(vt + (size_t)bh * 64 * SEQ);
#pragma unroll
    for (int i = 0; i < 8; ++i) {
        int p = i * 4096 + tid * 16;
        int lg = p ^ (((p >> 9) & 7) << 4);
        gload16(vg + lg, lds + ATT_V + p);
    }
    const char* qg = (const char*)(qb + ((size_t)bh * SEQ + mq * 64) * 64);
#pragma unroll
    for (int i = 0; i < 2; ++i) {
        int p = i * 4096 + tid * 16;
        int lg = p ^ (((p >> 7) & 7) << 4);
        gload16(qg + lg, lds + ATT_Q + p);
    }
    __syncthreads();

    int q0 = w * 16;
    int qg0 = mq * 64 + q0;

    f32x4 acc[16];
#pragma unroll
    for (int n = 0; n < 16; ++n) acc[n] = (f32x4){0.f, 0.f, 0.f, 0.f};
#pragma unroll
    for (int ks = 0; ks < 2; ++ks) {
        int rq = q0 + (lane & 15);
        int byq = (ks * 64 + ((lane >> 4) << 4)) ^ ((rq & 7) << 4);
        bf16x8 aq = *(const bf16x8*)(lds + ATT_Q + rq * 128 + byq);
#pragma unroll
        for (int n = 0; n < 16; ++n) {
            int rk = n * 16 + (lane & 15);
            int byk = (ks * 64 + ((lane >> 4) << 4)) ^ ((rk & 7) << 4);
            bf16x8 bk = *(const bf16x8*)(lds + ATT_K + rk * 128 + byk);
            acc[n] = __builtin_amdgcn_mfma_f32_16x16x32_bf16(aq, bk, acc[n], 0, 0, 0);
        }
    }
    __syncthreads();   // all K reads done; P may overwrite K region

    char* pbase = lds + ATT_K + w * 8192;   // per-wave [16][256] bf16
#pragma unroll
    for (int j = 0; j < 4; ++j) {
        int rql = ((lane >> 4) << 2) + j;
        int rg = qg0 + rql;
        float s[16];
        float m = -INFINITY;
#pragma unroll
        for (int n = 0; n < 16; ++n) {
            int cg = n * 16 + (lane & 15);
            float v = (cg <= rg) ? acc[n][j] * 0.125f : -INFINITY;
            s[n] = v;
            m = fmaxf(m, v);
        }
#pragma unroll
        for (int off = 1; off < 16; off <<= 1) m = fmaxf(m, __shfl_xor(m, off));
        float sum = 0.f;
#pragma unroll
        for (int n = 0; n < 16; ++n) { s[n] = __expf(s[n] - m); sum += s[n]; }
#pragma unroll
        for (int off = 1; off < 16; off <<= 1) sum += __shfl_xor(sum, off);
        float inv = 1.0f / sum;
#pragma unroll
        for (int n = 0; n < 16; ++n) {
            int cg = n * 16 + (lane & 15);
            int by = (cg * 2) ^ ((rql & 7) << 4);
            *(__hip_bfloat16*)(pbase + rql * 512 + by) = __float2bfloat16(s[n] * inv);
        }
    }

    f32x4 oacc[4];
#pragma unroll
    for (int nf = 0; nf < 4; ++nf) oacc[nf] = (f32x4){0.f, 0.f, 0.f, 0.f};
#pragma unroll
    for (int ks = 0; ks < 8; ++ks) {
        int rp = lane & 15;
        int byp = (ks * 64 + ((lane >> 4) << 4)) ^ ((rp & 7) << 4);
        bf16x8 ap = *(const bf16x8*)(pbase + rp * 512 + byp);
#pragma unroll
        for (int nf = 0; nf < 4; ++nf) {
            int rv = nf * 16 + (lane & 15);
            int byv = (ks * 64 + ((lane >> 4) << 4)) ^ ((rv & 7) << 4);
            bf16x8 bv = *(const bf16x8*)(lds + ATT_V + rv * 512 + byv);
            oacc[nf] = __builtin_amdgcn_mfma_f32_16x16x32_bf16(ap, bv, oacc[nf], 0, 0, 0);
        }
    }

#pragma unroll
    for (int nf = 0; nf < 4; ++nf) {
#pragma unroll
        for (int j = 0; j < 4; ++j) {
            int t = mq * 64 + q0 + ((lane >> 4) << 2) + j;
            int d = nf * 16 + (lane & 15);
            o[(size_t)(b * SEQ + t) * E_DIM + h * 64 + d] = __float2bfloat16(oacc[nf][j]);
        }
    }
}

extern "C" void kernel_launch(void* const* d_in, const int* in_sizes, int n_in,
                              void* d_out, int out_size, void* d_ws, size_t ws_size,
                              hipStream_t stream) {
    const int*   idx  = (const int*)d_in[0];
    const float* tok  = (const float*)d_in[1];
    const float* pos  = (const float*)d_in[2];
    const float* Wq   = (const float*)d_in[3];
    const float* Wk   = (const float*)d_in[4];
    const float* Wv   = (const float*)d_in[5];
    const float* Wo   = (const float*)d_in[6];
    const float* bo   = (const float*)d_in[7];
    const float* ln1g = (const float*)d_in[8];
    const float* ln1b = (const float*)d_in[9];
    const float* ln2g = (const float*)d_in[10];
    const float* ln2b = (const float*)d_in[11];
    const float* Wm   = (const float*)d_in[12];
    const float* bm   = (const float*)d_in[13];
    const float* lnfg = (const float*)d_in[14];
    const float* lnfb = (const float*)d_in[15];
    const float* Wlm  = (const float*)d_in[16];
    const float* blm  = (const float*)d_in[17];
    float* out = (float*)d_out;

    float*           x    = (float*)d_ws;                         // [4096][384] f32
    __hip_bfloat16*  hb   = (__hip_bfloat16*)(x + (size_t)NTOK * E_DIM);
    __hip_bfloat16*  WtL  = hb + (size_t)NTOK * E_DIM;
    __hip_bfloat16*  WtLM = WtL + (size_t)NLAYER * 1920 * E_DIM;  // [50432][384]
    __hip_bfloat16*  qbv  = WtLM + (size_t)VPAD2 * E_DIM;
    __hip_bfloat16*  kbv  = qbv + (size_t)NBH * SEQ * 64;
    __hip_bfloat16*  vtb  = kbv + (size_t)NBH * SEQ * 64;

    prep_kernel<<<1080 + LMTILES * 6 + NTOK / 4, 256, 0, stream>>>(
        Wq, Wk, Wv, Wo, Wm, Wlm, WtL, WtLM, idx, tok, pos, ln1g, ln1b, x, hb);

    for (int l = 0; l < NLAYER; ++l) {
        const __hip_bfloat16* wl = WtL + (size_t)l * 1920 * E_DIM;
        qkvgemm<<<dim3(QKV_N / 128, NTOK / 128), 256, 0, stream>>>(hb, wl, qbv, kbv, vtb);
        attn_fused<<<dim3(NBH, 4), 256, 0, stream>>>(qbv, kbv, vtb, hb);
        const float* ng = (l == NLAYER - 1) ? lnfg : ln1g + (l + 1) * E_DIM;
        const float* nb = (l == NLAYER - 1) ? lnfb : ln1b + (l + 1) * E_DIM;
        tail_fused<<<NTOK / 32, 256, 0, stream>>>(hb, wl + (size_t)1152 * E_DIM,
                                                  bo + l * E_DIM,
                                                  wl + (size_t)1536 * E_DIM,
                                                  bm + l * E_DIM,
                                                  x, x,
                                                  ln2g + l * E_DIM, ln2b + l * E_DIM,
                                                  ng, nb, hb);
    }

    mgemm_lm<<<dim3(VPAD2 / 256, NTOK / 128), 512, 0, stream>>>(hb, WtLM, blm, out);
}

// Round 13
// 707.287 us; speedup vs baseline: 1.0637x; 1.0431x over previous
//
#include <hip/hip_runtime.h>
#include <hip/hip_bf16.h>
#include <math.h>

#define E_DIM 384
#define N_HEAD 6
#define HEAD_SZ 64
#define SEQ 256
#define BATCH 16
#define NTOK 4096
#define NLAYER 6
#define VOCAB 50257
#define VPAD 50304          // 393*128
#define QKV_N 1152          // 3*E
#define NBH 96              // BATCH*N_HEAD

typedef __attribute__((ext_vector_type(8))) short bf16x8;
typedef __attribute__((ext_vector_type(4))) float f32x4;

__device__ __forceinline__ void gload16(const void* g, void* l) {
    __builtin_amdgcn_global_load_lds((const __attribute__((address_space(1))) char*)g,
                                     (__attribute__((address_space(3))) char*)l, 16, 0, 0);
}

__device__ __forceinline__ unsigned short bfbits(float x) {
    __hip_bfloat16 h = __float2bfloat16(x);
    return *reinterpret_cast<unsigned short*>(&h);
}

// ---------------- prep: weight transposes + embedding + LN1, one dispatch ------
__device__ __forceinline__ void tconv_tile(const float* __restrict__ src,
                                           __hip_bfloat16* __restrict__ dst,
                                           int K, int N, int n0, int k0) {
    __shared__ float tbuf[64][65];
    int c = threadIdx.x & 63, r4 = threadIdx.x >> 6;
#pragma unroll
    for (int i = 0; i < 16; ++i) {
        int r = r4 * 16 + i;
        float v = 0.f;
        if (n0 + c < N) v = src[(size_t)(k0 + r) * N + n0 + c];
        tbuf[r][c] = v;
    }
    __syncthreads();
#pragma unroll
    for (int i = 0; i < 16; ++i) {
        int rn = r4 * 16 + i;
        dst[(size_t)(n0 + rn) * K + k0 + c] = __float2bfloat16(tbuf[c][rn]);
    }
}

__global__ __launch_bounds__(256) void prep_kernel(const float* __restrict__ Wq,
                                                   const float* __restrict__ Wk,
                                                   const float* __restrict__ Wv,
                                                   const float* __restrict__ Wo,
                                                   const float* __restrict__ Wm,
                                                   const float* __restrict__ Wlm,
                                                   __hip_bfloat16* __restrict__ WtL,
                                                   __hip_bfloat16* __restrict__ WtLM,
                                                   const int* __restrict__ idx,
                                                   const float* __restrict__ tok,
                                                   const float* __restrict__ pos,
                                                   const float* __restrict__ g,
                                                   const float* __restrict__ b,
                                                   float* __restrict__ x,
                                                   __hip_bfloat16* __restrict__ h) {
    int bid = blockIdx.x;
    if (bid < 1080) {              // per-layer weights: 30 z-slices x 36 tiles
        int z = bid / 36, rem = bid - z * 36;
        int bx = rem % 6, by = rem / 6;
        int l = z / 5, t = z - l * 5;
        const float* src;
        int dstoff;
        switch (t) {
            case 0: src = Wq; dstoff = 0;    break;
            case 1: src = Wk; dstoff = 384;  break;
            case 2: src = Wv; dstoff = 768;  break;
            case 3: src = Wo; dstoff = 1152; break;
            default: src = Wm; dstoff = 1536;
        }
        src += (size_t)l * E_DIM * E_DIM;
        __hip_bfloat16* dst = WtL + ((size_t)l * 1920 + dstoff) * E_DIM;
        tconv_tile(src, dst, E_DIM, E_DIM, bx * 64, by * 64);
    } else if (bid < 1080 + 786 * 6) {   // LM head transpose
        int b2 = bid - 1080;
        int bx = b2 % 786, by = b2 / 786;
        tconv_tile(Wlm, WtLM, E_DIM, VOCAB, bx * 64, by * 64);
    } else {                       // embedding + LN1: 1024 blocks x 4 rows
        int rb = bid - (1080 + 786 * 6);
        int lane = threadIdx.x & 63;
        int w = threadIdx.x >> 6;
        int row = rb * 4 + w;
        int t = row & (SEQ - 1);
        const float* tr = tok + (size_t)idx[row] * E_DIM;
        const float* pr = pos + (size_t)t * E_DIM;
        float* xr = x + (size_t)row * E_DIM;
        float v[6];
        float s = 0.f;
#pragma unroll
        for (int c = 0; c < 6; ++c) {
            int e = lane + 64 * c;
            v[c] = tr[e] + pr[e];
            xr[e] = v[c];
            s += v[c];
        }
#pragma unroll
        for (int off = 32; off > 0; off >>= 1) s += __shfl_xor(s, off);
        float mu = s * (1.0f / E_DIM);
        float s2 = 0.f;
#pragma unroll
        for (int c = 0; c < 6; ++c) { float d = v[c] - mu; s2 += d * d; }
#pragma unroll
        for (int off = 32; off > 0; off >>= 1) s2 += __shfl_xor(s2, off);
        float rstd = rsqrtf(s2 * (1.0f / E_DIM) + 1e-5f);
        __hip_bfloat16* hr = h + (size_t)row * E_DIM;
#pragma unroll
        for (int c = 0; c < 6; ++c) {
            int e = lane + 64 * c;
            hr[e] = __float2bfloat16((v[c] - mu) * rstd * g[e] + b[e]);
        }
    }
}

// ---------------- QKV GEMM (issue-early double-buffered staging) ------
__global__ __launch_bounds__(256) void qkvgemm(const __hip_bfloat16* __restrict__ A,
                                               const __hip_bfloat16* __restrict__ Bt,
                                               __hip_bfloat16* __restrict__ qb,
                                               __hip_bfloat16* __restrict__ kb,
                                               __hip_bfloat16* __restrict__ vt) {
    __shared__ __align__(1024) char lds[65536];   // [buf][A 16K | B 16K]
    int tid = threadIdx.x;
    int lane = tid & 63, w = tid >> 6;
    int wm = w >> 1, wn = w & 1;
    int row0 = blockIdx.y * 128;
    int col0 = blockIdx.x * 128;

    f32x4 acc[4][4];
#pragma unroll
    for (int i = 0; i < 4; ++i)
#pragma unroll
        for (int j = 0; j < 4; ++j) acc[i][j] = (f32x4){0.f, 0.f, 0.f, 0.f};

    auto stage = [&](int buf, int k0) {
        char* Ab = lds + buf * 32768;
        char* Bb = Ab + 16384;
#pragma unroll
        for (int i = 0; i < 4; ++i) {
            int p  = i * 4096 + tid * 16;
            int lg = p ^ (((p >> 7) & 7) << 4);
            int r  = lg >> 7, cb = lg & 127;
            gload16((const char*)(A  + (size_t)(row0 + r) * E_DIM + k0) + cb, Ab + i * 4096 + w * 1024);
            gload16((const char*)(Bt + (size_t)(col0 + r) * E_DIM + k0) + cb, Bb + i * 4096 + w * 1024);
        }
    };

    stage(0, 0);
    for (int kt = 0; kt < 6; ++kt) {
        __syncthreads();
        if (kt < 5) stage((kt + 1) & 1, (kt + 1) * 64);
        const char* Ab = lds + (kt & 1) * 32768;
        const char* Bb = Ab + 16384;
#pragma unroll
        for (int ks = 0; ks < 2; ++ks) {
            bf16x8 af[4], bfr[4];
#pragma unroll
            for (int mi = 0; mi < 4; ++mi) {
                int rl = wm * 64 + mi * 16 + (lane & 15);
                int lg = rl * 128 + ks * 64 + ((lane >> 4) << 4);
                int ph = lg ^ ((rl & 7) << 4);
                af[mi] = *(const bf16x8*)(Ab + ph);
            }
#pragma unroll
            for (int ni = 0; ni < 4; ++ni) {
                int rl = wn * 64 + ni * 16 + (lane & 15);
                int lg = rl * 128 + ks * 64 + ((lane >> 4) << 4);
                int ph = lg ^ ((rl & 7) << 4);
                bfr[ni] = *(const bf16x8*)(Bb + ph);
            }
#pragma unroll
            for (int mi = 0; mi < 4; ++mi)
#pragma unroll
                for (int ni = 0; ni < 4; ++ni)
                    acc[mi][ni] = __builtin_amdgcn_mfma_f32_16x16x32_bf16(
                        af[mi], bfr[ni], acc[mi][ni], 0, 0, 0);
        }
    }

#pragma unroll
    for (int mi = 0; mi < 4; ++mi) {
#pragma unroll
        for (int ni = 0; ni < 4; ++ni) {
            int gcl = col0 + wn * 64 + ni * 16 + (lane & 15);   // 0..1151
            int which = gcl / 384;
            int rem = gcl - which * 384;
            int h = rem >> 6, d = rem & 63;
            int gr0 = row0 + wm * 64 + mi * 16 + ((lane >> 4) << 2);
#pragma unroll
            for (int j = 0; j < 4; ++j) {
                int gr = gr0 + j;
                int b = gr >> 8, t = gr & 255;
                int bh = b * N_HEAD + h;
                __hip_bfloat16 v = __float2bfloat16(acc[mi][ni][j]);
                if (which == 0)      qb[(((size_t)bh << 8) + t) * 64 + d] = v;
                else if (which == 1) kb[(((size_t)bh << 8) + t) * 64 + d] = v;
                else                 vt[(((size_t)bh << 6) + d) * SEQ + t] = v;
            }
        }
    }
}

// ---------------- fused layer tail: proj+res+LN2+MLP+res+LN(next) -----------
__global__ __launch_bounds__(256) void tail_fused(const __hip_bfloat16* __restrict__ A,
                                                  const __hip_bfloat16* __restrict__ WoT,
                                                  const float* __restrict__ bo,
                                                  const __hip_bfloat16* __restrict__ WmT,
                                                  const float* __restrict__ bm,
                                                  const float* __restrict__ xin,
                                                  float* __restrict__ xout,
                                                  const float* __restrict__ g2,
                                                  const float* __restrict__ b2v,
                                                  const float* __restrict__ gn,
                                                  const float* __restrict__ bnv,
                                                  __hip_bfloat16* __restrict__ hout) {
    __shared__ __align__(1024) char lds[131072];
    char* Bbuf = lds;                       // + buf*49152
    char* Abuf = lds + 98304;               // + buf*4096
    float* xt  = (float*)(lds + 49152);
    char* h2   = lds + 106496;              // [32 rows][768B], XOR-swizzled
    int tid = threadIdx.x;
    int lane = tid & 63, w = tid >> 6;
    int row0 = blockIdx.x * 32;

    float xnew[2][6][4];
#pragma unroll
    for (int mi = 0; mi < 2; ++mi)
#pragma unroll
        for (int ni = 0; ni < 6; ++ni) {
            int gc = w * 96 + ni * 16 + (lane & 15);
            int lr0 = mi * 16 + ((lane >> 4) << 2);
#pragma unroll
            for (int j = 0; j < 4; ++j)
                xnew[mi][ni][j] = xin[(size_t)(row0 + lr0 + j) * E_DIM + gc];
        }

    f32x4 acc[2][6];
#pragma unroll
    for (int i = 0; i < 2; ++i)
#pragma unroll
        for (int j = 0; j < 6; ++j) acc[i][j] = (f32x4){0.f, 0.f, 0.f, 0.f};

    auto stageB = [&](const __hip_bfloat16* Bt, int buf, int k0) {
        char* Bb = Bbuf + buf * 49152;
#pragma unroll
        for (int i = 0; i < 12; ++i) {
            int p  = i * 4096 + tid * 16;
            int lg = p ^ (((p >> 7) & 7) << 4);
            int r  = lg >> 7, cb = lg & 127;
            gload16((const char*)(Bt + (size_t)r * E_DIM + k0) + cb, Bb + i * 4096 + w * 1024);
        }
    };
    auto stageA = [&](int buf, int k0) {
        int p  = tid * 16;
        int lg = p ^ (((p >> 7) & 7) << 4);
        int r  = lg >> 7, cb = lg & 127;
        gload16((const char*)(A + (size_t)(row0 + r) * E_DIM + k0) + cb,
                Abuf + buf * 4096 + w * 1024);
    };

    // ================= proj GEMM =================
    stageA(0, 0);
    stageB(WoT, 0, 0);
    for (int kt = 0; kt < 6; ++kt) {
        __syncthreads();
        if (kt < 5) { stageA((kt + 1) & 1, (kt + 1) * 64); stageB(WoT, (kt + 1) & 1, (kt + 1) * 64); }
        const char* Ab = Abuf + (kt & 1) * 4096;
        const char* Bb = Bbuf + (kt & 1) * 49152;
#pragma unroll
        for (int ks = 0; ks < 2; ++ks) {
            bf16x8 af[2], bfr[6];
#pragma unroll
            for (int mi = 0; mi < 2; ++mi) {
                int rl = mi * 16 + (lane & 15);
                int lg = rl * 128 + ks * 64 + ((lane >> 4) << 4);
                int ph = lg ^ ((rl & 7) << 4);
                af[mi] = *(const bf16x8*)(Ab + ph);
            }
#pragma unroll
            for (int ni = 0; ni < 6; ++ni) {
                int rl = w * 96 + ni * 16 + (lane & 15);
                int lg = rl * 128 + ks * 64 + ((lane >> 4) << 4);
                int ph = lg ^ ((rl & 7) << 4);
                bfr[ni] = *(const bf16x8*)(Bb + ph);
            }
#pragma unroll
            for (int mi = 0; mi < 2; ++mi)
#pragma unroll
                for (int ni = 0; ni < 6; ++ni)
                    acc[mi][ni] = __builtin_amdgcn_mfma_f32_16x16x32_bf16(
                        af[mi], bfr[ni], acc[mi][ni], 0, 0, 0);
        }
    }
    __syncthreads();
    stageB(WmT, 0, 0);          // prefetch Wm chunk0 under LN2

#pragma unroll
    for (int mi = 0; mi < 2; ++mi) {
#pragma unroll
        for (int ni = 0; ni < 6; ++ni) {
            int gc = w * 96 + ni * 16 + (lane & 15);
            int lr0 = mi * 16 + ((lane >> 4) << 2);
            float bv = bo[gc];
#pragma unroll
            for (int j = 0; j < 4; ++j) {
                float xn = xnew[mi][ni][j] + acc[mi][ni][j] + bv;
                xnew[mi][ni][j] = xn;
                xt[(lr0 + j) * 392 + gc] = xn;
            }
        }
    }
    __syncthreads();

#pragma unroll
    for (int r8 = 0; r8 < 8; ++r8) {
        int r = w * 8 + r8;
        float v[6];
        float s = 0.f;
#pragma unroll
        for (int c = 0; c < 6; ++c) { v[c] = xt[r * 392 + lane + 64 * c]; s += v[c]; }
#pragma unroll
        for (int off = 32; off > 0; off >>= 1) s += __shfl_xor(s, off);
        float mu = s * (1.0f / E_DIM);
        float s2 = 0.f;
#pragma unroll
        for (int c = 0; c < 6; ++c) { float d = v[c] - mu; s2 += d * d; }
#pragma unroll
        for (int off = 32; off > 0; off >>= 1) s2 += __shfl_xor(s2, off);
        float rstd = rsqrtf(s2 * (1.0f / E_DIM) + 1e-5f);
#pragma unroll
        for (int c = 0; c < 6; ++c) {
            int e = lane + 64 * c;
            unsigned short u = bfbits((v[c] - mu) * rstd * g2[e] + b2v[e]);
            int by = (2 * e) ^ ((r & 7) << 4);
            *(unsigned short*)(h2 + r * 768 + by) = u;
        }
    }

    // ================= MLP GEMM (A from h2 LDS) =================
#pragma unroll
    for (int i = 0; i < 2; ++i)
#pragma unroll
        for (int j = 0; j < 6; ++j) acc[i][j] = (f32x4){0.f, 0.f, 0.f, 0.f};

    for (int kt = 0; kt < 6; ++kt) {
        __syncthreads();
        if (kt < 5) stageB(WmT, (kt + 1) & 1, (kt + 1) * 64);
        const char* Bb = Bbuf + (kt & 1) * 49152;
#pragma unroll
        for (int ks = 0; ks < 2; ++ks) {
            bf16x8 af[2], bfr[6];
#pragma unroll
            for (int mi = 0; mi < 2; ++mi) {
                int rl = mi * 16 + (lane & 15);
                int koff = kt * 128 + ks * 64 + ((lane >> 4) << 4);
                int by = koff ^ ((rl & 7) << 4);
                af[mi] = *(const bf16x8*)(h2 + rl * 768 + by);
            }
#pragma unroll
            for (int ni = 0; ni < 6; ++ni) {
                int rl = w * 96 + ni * 16 + (lane & 15);
                int lg = rl * 128 + ks * 64 + ((lane >> 4) << 4);
                int ph = lg ^ ((rl & 7) << 4);
                bfr[ni] = *(const bf16x8*)(Bb + ph);
            }
#pragma unroll
            for (int mi = 0; mi < 2; ++mi)
#pragma unroll
                for (int ni = 0; ni < 6; ++ni)
                    acc[mi][ni] = __builtin_amdgcn_mfma_f32_16x16x32_bf16(
                        af[mi], bfr[ni], acc[mi][ni], 0, 0, 0);
        }
    }
    __syncthreads();

#pragma unroll
    for (int mi = 0; mi < 2; ++mi) {
#pragma unroll
        for (int ni = 0; ni < 6; ++ni) {
            int gc = w * 96 + ni * 16 + (lane & 15);
            int lr0 = mi * 16 + ((lane >> 4) << 2);
            float bv = bm[gc];
#pragma unroll
            for (int j = 0; j < 4; ++j) {
                float u = fmaxf(acc[mi][ni][j] + bv, 0.f);
                float xn = xnew[mi][ni][j] + u;
                xout[(size_t)(row0 + lr0 + j) * E_DIM + gc] = xn;
                xt[(lr0 + j) * 392 + gc] = xn;
            }
        }
    }
    __syncthreads();

#pragma unroll
    for (int r8 = 0; r8 < 8; ++r8) {
        int r = w * 8 + r8;
        float v[6];
        float s = 0.f;
#pragma unroll
        for (int c = 0; c < 6; ++c) { v[c] = xt[r * 392 + lane + 64 * c]; s += v[c]; }
#pragma unroll
        for (int off = 32; off > 0; off >>= 1) s += __shfl_xor(s, off);
        float mu = s * (1.0f / E_DIM);
        float s2 = 0.f;
#pragma unroll
        for (int c = 0; c < 6; ++c) { float d = v[c] - mu; s2 += d * d; }
#pragma unroll
        for (int off = 32; off > 0; off >>= 1) s2 += __shfl_xor(s2, off);
        float rstd = rsqrtf(s2 * (1.0f / E_DIM) + 1e-5f);
        __hip_bfloat16* hr = hout + (size_t)(row0 + r) * E_DIM;
#pragma unroll
        for (int c = 0; c < 6; ++c) {
            int e = lane + 64 * c;
            hr[e] = __float2bfloat16((v[c] - mu) * rstd * gn[e] + bnv[e]);
        }
    }
}

// ---------------- LM-head GEMM: 128x128 tile, 8 waves (2x4), low-AGPR --------
// Same tile/order/arithmetic as the R10-best kernel; only the wave->subtile
// decomposition changes: 8 waves x (64x32) -> acc[4][2] = 32 AGPR/lane (was
// 64), cutting total regs/lane ~160 -> ~120 so occupancy rises ~12 -> 16
// waves/CU. Theory: mgemm_lm is TLP-bound (occupancy 21% in R9 profile; all
// bandwidth-side levers were null), so +33% resident waves -> less un-hidden
// stage-drain. bx-major bijective XCD swizzle (write locality) unchanged.
__global__ __launch_bounds__(512) void mgemm_lm(const __hip_bfloat16* __restrict__ A,
                                                const __hip_bfloat16* __restrict__ Bt,
                                                const float* __restrict__ bias,
                                                float* __restrict__ C) {
    __shared__ __align__(1024) char lds[32768];
    char* Ar = lds;
    char* Br = lds + 16384;
    int tid = threadIdx.x;
    int lane = tid & 63, w = tid >> 6;            // 8 waves
    int wm = w >> 2, wn = w & 3;                  // 2 x 4 -> each wave 64r x 32c

    // bijective XCD swizzle: grid 393x32 = 12576 = 8*1572, bx-major within XCD
    int wg  = blockIdx.y * 393 + blockIdx.x;
    int swz = (wg & 7) * 1572 + (wg >> 3);
    int bx  = swz % 393, by = swz / 393;
    int row0 = by * 128;
    int col0 = bx * 128;

    f32x4 acc[4][2];
#pragma unroll
    for (int i = 0; i < 4; ++i)
#pragma unroll
        for (int j = 0; j < 2; ++j) acc[i][j] = (f32x4){0.f, 0.f, 0.f, 0.f};

    for (int k0 = 0; k0 < E_DIM; k0 += 64) {
        __syncthreads();
#pragma unroll
        for (int i = 0; i < 2; ++i) {   // A: 16KB, 512 thr x 16B x 2
            int p  = i * 8192 + tid * 16;
            int lg = p ^ (((p >> 7) & 7) << 4);
            int r  = lg >> 7, cb = lg & 127;
            gload16((const char*)(A  + (size_t)(row0 + r) * E_DIM + k0) + cb, Ar + i * 8192 + w * 1024);
        }
#pragma unroll
        for (int i = 0; i < 2; ++i) {   // B: 16KB
            int p  = i * 8192 + tid * 16;
            int lg = p ^ (((p >> 7) & 7) << 4);
            int r  = lg >> 7, cb = lg & 127;
            gload16((const char*)(Bt + (size_t)(col0 + r) * E_DIM + k0) + cb, Br + i * 8192 + w * 1024);
        }
        __syncthreads();
#pragma unroll
        for (int ks = 0; ks < 2; ++ks) {
            bf16x8 af[4], bfr[2];
#pragma unroll
            for (int mi = 0; mi < 4; ++mi) {
                int rl = wm * 64 + mi * 16 + (lane & 15);
                int lg = rl * 128 + ks * 64 + ((lane >> 4) << 4);
                int ph = lg ^ ((rl & 7) << 4);
                af[mi] = *(const bf16x8*)(Ar + ph);
            }
#pragma unroll
            for (int ni = 0; ni < 2; ++ni) {
                int rl = wn * 32 + ni * 16 + (lane & 15);
                int lg = rl * 128 + ks * 64 + ((lane >> 4) << 4);
                int ph = lg ^ ((rl & 7) << 4);
                bfr[ni] = *(const bf16x8*)(Br + ph);
            }
#pragma unroll
            for (int mi = 0; mi < 4; ++mi)
#pragma unroll
                for (int ni = 0; ni < 2; ++ni)
                    acc[mi][ni] = __builtin_amdgcn_mfma_f32_16x16x32_bf16(
                        af[mi], bfr[ni], acc[mi][ni], 0, 0, 0);
        }
    }

#pragma unroll
    for (int mi = 0; mi < 4; ++mi) {
#pragma unroll
        for (int ni = 0; ni < 2; ++ni) {
            int gr = row0 + wm * 64 + mi * 16 + ((lane >> 4) << 2);
            int gc = col0 + wn * 32 + ni * 16 + (lane & 15);
            if (gc < VOCAB) {
                float bv = bias[gc];
#pragma unroll
                for (int j = 0; j < 4; ++j)
                    C[(size_t)(gr + j) * VOCAB + gc] = acc[mi][ni][j] + bv;
            }
        }
    }
}

// ---------------- fused MFMA attention (72 KB LDS, P aliases K) -------
#define ATT_K 0
#define ATT_V 32768
#define ATT_Q 65536

__global__ __launch_bounds__(256) void attn_fused(const __hip_bfloat16* __restrict__ qb,
                                                  const __hip_bfloat16* __restrict__ kb,
                                                  const __hip_bfloat16* __restrict__ vt,
                                                  __hip_bfloat16* __restrict__ o) {
    __shared__ __align__(1024) char lds[73728];
    int tid = threadIdx.x;
    int lane = tid & 63, w = tid >> 6;
    int bh = blockIdx.x;
    int mq = blockIdx.y;
    int b = bh / N_HEAD, h = bh - b * N_HEAD;

    const char* kg = (const char*)(kb + (size_t)bh * SEQ * 64);
#pragma unroll
    for (int i = 0; i < 8; ++i) {
        int p = i * 4096 + tid * 16;
        int lg = p ^ (((p >> 7) & 7) << 4);
        gload16(kg + lg, lds + ATT_K + p);
    }
    const char* vg = (const char*)(vt + (size_t)bh * 64 * SEQ);
#pragma unroll
    for (int i = 0; i < 8; ++i) {
        int p = i * 4096 + tid * 16;
        int lg = p ^ (((p >> 9) & 7) << 4);
        gload16(vg + lg, lds + ATT_V + p);
    }
    const char* qg = (const char*)(qb + ((size_t)bh * SEQ + mq * 64) * 64);
#pragma unroll
    for (int i = 0; i < 2; ++i) {
        int p = i * 4096 + tid * 16;
        int lg = p ^ (((p >> 7) & 7) << 4);
        gload16(qg + lg, lds + ATT_Q + p);
    }
    __syncthreads();

    int q0 = w * 16;
    int qg0 = mq * 64 + q0;

    f32x4 acc[16];
#pragma unroll
    for (int n = 0; n < 16; ++n) acc[n] = (f32x4){0.f, 0.f, 0.f, 0.f};
#pragma unroll
    for (int ks = 0; ks < 2; ++ks) {
        int rq = q0 + (lane & 15);
        int byq = (ks * 64 + ((lane >> 4) << 4)) ^ ((rq & 7) << 4);
        bf16x8 aq = *(const bf16x8*)(lds + ATT_Q + rq * 128 + byq);
#pragma unroll
        for (int n = 0; n < 16; ++n) {
            int rk = n * 16 + (lane & 15);
            int byk = (ks * 64 + ((lane >> 4) << 4)) ^ ((rk & 7) << 4);
            bf16x8 bk = *(const bf16x8*)(lds + ATT_K + rk * 128 + byk);
            acc[n] = __builtin_amdgcn_mfma_f32_16x16x32_bf16(aq, bk, acc[n], 0, 0, 0);
        }
    }
    __syncthreads();   // all K reads done; P may overwrite K region

    char* pbase = lds + ATT_K + w * 8192;   // per-wave [16][256] bf16
#pragma unroll
    for (int j = 0; j < 4; ++j) {
        int rql = ((lane >> 4) << 2) + j;
        int rg = qg0 + rql;
        float s[16];
        float m = -INFINITY;
#pragma unroll
        for (int n = 0; n < 16; ++n) {
            int cg = n * 16 + (lane & 15);
            float v = (cg <= rg) ? acc[n][j] * 0.125f : -INFINITY;
            s[n] = v;
            m = fmaxf(m, v);
        }
#pragma unroll
        for (int off = 1; off < 16; off <<= 1) m = fmaxf(m, __shfl_xor(m, off));
        float sum = 0.f;
#pragma unroll
        for (int n = 0; n < 16; ++n) { s[n] = __expf(s[n] - m); sum += s[n]; }
#pragma unroll
        for (int off = 1; off < 16; off <<= 1) sum += __shfl_xor(sum, off);
        float inv = 1.0f / sum;
#pragma unroll
        for (int n = 0; n < 16; ++n) {
            int cg = n * 16 + (lane & 15);
            int by = (cg * 2) ^ ((rql & 7) << 4);
            *(__hip_bfloat16*)(pbase + rql * 512 + by) = __float2bfloat16(s[n] * inv);
        }
    }

    f32x4 oacc[4];
#pragma unroll
    for (int nf = 0; nf < 4; ++nf) oacc[nf] = (f32x4){0.f, 0.f, 0.f, 0.f};
#pragma unroll
    for (int ks = 0; ks < 8; ++ks) {
        int rp = lane & 15;
        int byp = (ks * 64 + ((lane >> 4) << 4)) ^ ((rp & 7) << 4);
        bf16x8 ap = *(const bf16x8*)(pbase + rp * 512 + byp);
#pragma unroll
        for (int nf = 0; nf < 4; ++nf) {
            int rv = nf * 16 + (lane & 15);
            int byv = (ks * 64 + ((lane >> 4) << 4)) ^ ((rv & 7) << 4);
            bf16x8 bv = *(const bf16x8*)(lds + ATT_V + rv * 512 + byv);
            oacc[nf] = __builtin_amdgcn_mfma_f32_16x16x32_bf16(ap, bv, oacc[nf], 0, 0, 0);
        }
    }

#pragma unroll
    for (int nf = 0; nf < 4; ++nf) {
#pragma unroll
        for (int j = 0; j < 4; ++j) {
            int t = mq * 64 + q0 + ((lane >> 4) << 2) + j;
            int d = nf * 16 + (lane & 15);
            o[(size_t)(b * SEQ + t) * E_DIM + h * 64 + d] = __float2bfloat16(oacc[nf][j]);
        }
    }
}

extern "C" void kernel_launch(void* const* d_in, const int* in_sizes, int n_in,
                              void* d_out, int out_size, void* d_ws, size_t ws_size,
                              hipStream_t stream) {
    const int*   idx  = (const int*)d_in[0];
    const float* tok  = (const float*)d_in[1];
    const float* pos  = (const float*)d_in[2];
    const float* Wq   = (const float*)d_in[3];
    const float* Wk   = (const float*)d_in[4];
    const float* Wv   = (const float*)d_in[5];
    const float* Wo   = (const float*)d_in[6];
    const float* bo   = (const float*)d_in[7];
    const float* ln1g = (const float*)d_in[8];
    const float* ln1b = (const float*)d_in[9];
    const float* ln2g = (const float*)d_in[10];
    const float* ln2b = (const float*)d_in[11];
    const float* Wm   = (const float*)d_in[12];
    const float* bm   = (const float*)d_in[13];
    const float* lnfg = (const float*)d_in[14];
    const float* lnfb = (const float*)d_in[15];
    const float* Wlm  = (const float*)d_in[16];
    const float* blm  = (const float*)d_in[17];
    float* out = (float*)d_out;

    float*           x    = (float*)d_ws;                         // [4096][384] f32
    __hip_bfloat16*  hb   = (__hip_bfloat16*)(x + (size_t)NTOK * E_DIM);
    __hip_bfloat16*  WtL  = hb + (size_t)NTOK * E_DIM;
    __hip_bfloat16*  WtLM = WtL + (size_t)NLAYER * 1920 * E_DIM;  // [50304][384]
    __hip_bfloat16*  qbv  = WtLM + (size_t)VPAD * E_DIM;
    __hip_bfloat16*  kbv  = qbv + (size_t)NBH * SEQ * 64;
    __hip_bfloat16*  vtb  = kbv + (size_t)NBH * SEQ * 64;

    prep_kernel<<<1080 + 786 * 6 + NTOK / 4, 256, 0, stream>>>(
        Wq, Wk, Wv, Wo, Wm, Wlm, WtL, WtLM, idx, tok, pos, ln1g, ln1b, x, hb);

    for (int l = 0; l < NLAYER; ++l) {
        const __hip_bfloat16* wl = WtL + (size_t)l * 1920 * E_DIM;
        qkvgemm<<<dim3(QKV_N / 128, NTOK / 128), 256, 0, stream>>>(hb, wl, qbv, kbv, vtb);
        attn_fused<<<dim3(NBH, 4), 256, 0, stream>>>(qbv, kbv, vtb, hb);
        const float* ng = (l == NLAYER - 1) ? lnfg : ln1g + (l + 1) * E_DIM;
        const float* nb = (l == NLAYER - 1) ? lnfb : ln1b + (l + 1) * E_DIM;
        tail_fused<<<NTOK / 32, 256, 0, stream>>>(hb, wl + (size_t)1152 * E_DIM,
                                                  bo + l * E_DIM,
                                                  wl + (size_t)1536 * E_DIM,
                                                  bm + l * E_DIM,
                                                  x, x,
                                                  ln2g + l * E_DIM, ln2b + l * E_DIM,
                                                  ng, nb, hb);
    }

    mgemm_lm<<<dim3(VPAD / 128, NTOK / 128), 512, 0, stream>>>(hb, WtLM, blm, out);
}

// Round 14
// 700.484 us; speedup vs baseline: 1.0741x; 1.0097x over previous
//
#include <hip/hip_runtime.h>
#include <hip/hip_bf16.h>
#include <math.h>

#define E_DIM 384
#define N_HEAD 6
#define HEAD_SZ 64
#define SEQ 256
#define BATCH 16
#define NTOK 4096
#define NLAYER 6
#define VOCAB 50257
#define VPAD 50304          // 393*128
#define QKV_N 1152          // 3*E
#define NBH 96              // BATCH*N_HEAD

typedef __attribute__((ext_vector_type(8))) short bf16x8;
typedef __attribute__((ext_vector_type(4))) float f32x4;

__device__ __forceinline__ void gload16(const void* g, void* l) {
    __builtin_amdgcn_global_load_lds((const __attribute__((address_space(1))) char*)g,
                                     (__attribute__((address_space(3))) char*)l, 16, 0, 0);
}

__device__ __forceinline__ unsigned short bfbits(float x) {
    __hip_bfloat16 h = __float2bfloat16(x);
    return *reinterpret_cast<unsigned short*>(&h);
}

// ---------------- prep: weight transposes + embedding + LN1, one dispatch ------
__device__ __forceinline__ void tconv_tile(const float* __restrict__ src,
                                           __hip_bfloat16* __restrict__ dst,
                                           int K, int N, int n0, int k0) {
    __shared__ float tbuf[64][65];
    int c = threadIdx.x & 63, r4 = threadIdx.x >> 6;
#pragma unroll
    for (int i = 0; i < 16; ++i) {
        int r = r4 * 16 + i;
        float v = 0.f;
        if (n0 + c < N) v = src[(size_t)(k0 + r) * N + n0 + c];
        tbuf[r][c] = v;
    }
    __syncthreads();
#pragma unroll
    for (int i = 0; i < 16; ++i) {
        int rn = r4 * 16 + i;
        dst[(size_t)(n0 + rn) * K + k0 + c] = __float2bfloat16(tbuf[c][rn]);
    }
}

__global__ __launch_bounds__(256) void prep_kernel(const float* __restrict__ Wq,
                                                   const float* __restrict__ Wk,
                                                   const float* __restrict__ Wv,
                                                   const float* __restrict__ Wo,
                                                   const float* __restrict__ Wm,
                                                   const float* __restrict__ Wlm,
                                                   __hip_bfloat16* __restrict__ WtL,
                                                   __hip_bfloat16* __restrict__ WtLM,
                                                   const int* __restrict__ idx,
                                                   const float* __restrict__ tok,
                                                   const float* __restrict__ pos,
                                                   const float* __restrict__ g,
                                                   const float* __restrict__ b,
                                                   float* __restrict__ x,
                                                   __hip_bfloat16* __restrict__ h) {
    int bid = blockIdx.x;
    if (bid < 1080) {              // per-layer weights: 30 z-slices x 36 tiles
        int z = bid / 36, rem = bid - z * 36;
        int bx = rem % 6, by = rem / 6;
        int l = z / 5, t = z - l * 5;
        const float* src;
        int dstoff;
        switch (t) {
            case 0: src = Wq; dstoff = 0;    break;
            case 1: src = Wk; dstoff = 384;  break;
            case 2: src = Wv; dstoff = 768;  break;
            case 3: src = Wo; dstoff = 1152; break;
            default: src = Wm; dstoff = 1536;
        }
        src += (size_t)l * E_DIM * E_DIM;
        __hip_bfloat16* dst = WtL + ((size_t)l * 1920 + dstoff) * E_DIM;
        tconv_tile(src, dst, E_DIM, E_DIM, bx * 64, by * 64);
    } else if (bid < 1080 + 786 * 6) {   // LM head transpose
        int b2 = bid - 1080;
        int bx = b2 % 786, by = b2 / 786;
        tconv_tile(Wlm, WtLM, E_DIM, VOCAB, bx * 64, by * 64);
    } else {                       // embedding + LN1: 1024 blocks x 4 rows
        int rb = bid - (1080 + 786 * 6);
        int lane = threadIdx.x & 63;
        int w = threadIdx.x >> 6;
        int row = rb * 4 + w;
        int t = row & (SEQ - 1);
        const float* tr = tok + (size_t)idx[row] * E_DIM;
        const float* pr = pos + (size_t)t * E_DIM;
        float* xr = x + (size_t)row * E_DIM;
        float v[6];
        float s = 0.f;
#pragma unroll
        for (int c = 0; c < 6; ++c) {
            int e = lane + 64 * c;
            v[c] = tr[e] + pr[e];
            xr[e] = v[c];
            s += v[c];
        }
#pragma unroll
        for (int off = 32; off > 0; off >>= 1) s += __shfl_xor(s, off);
        float mu = s * (1.0f / E_DIM);
        float s2 = 0.f;
#pragma unroll
        for (int c = 0; c < 6; ++c) { float d = v[c] - mu; s2 += d * d; }
#pragma unroll
        for (int off = 32; off > 0; off >>= 1) s2 += __shfl_xor(s2, off);
        float rstd = rsqrtf(s2 * (1.0f / E_DIM) + 1e-5f);
        __hip_bfloat16* hr = h + (size_t)row * E_DIM;
#pragma unroll
        for (int c = 0; c < 6; ++c) {
            int e = lane + 64 * c;
            hr[e] = __float2bfloat16((v[c] - mu) * rstd * g[e] + b[e]);
        }
    }
}

// ---------------- QKV GEMM (issue-early double-buffered staging) ------
__global__ __launch_bounds__(256) void qkvgemm(const __hip_bfloat16* __restrict__ A,
                                               const __hip_bfloat16* __restrict__ Bt,
                                               __hip_bfloat16* __restrict__ qb,
                                               __hip_bfloat16* __restrict__ kb,
                                               __hip_bfloat16* __restrict__ vt) {
    __shared__ __align__(1024) char lds[65536];   // [buf][A 16K | B 16K]
    int tid = threadIdx.x;
    int lane = tid & 63, w = tid >> 6;
    int wm = w >> 1, wn = w & 1;
    int row0 = blockIdx.y * 128;
    int col0 = blockIdx.x * 128;

    f32x4 acc[4][4];
#pragma unroll
    for (int i = 0; i < 4; ++i)
#pragma unroll
        for (int j = 0; j < 4; ++j) acc[i][j] = (f32x4){0.f, 0.f, 0.f, 0.f};

    auto stage = [&](int buf, int k0) {
        char* Ab = lds + buf * 32768;
        char* Bb = Ab + 16384;
#pragma unroll
        for (int i = 0; i < 4; ++i) {
            int p  = i * 4096 + tid * 16;
            int lg = p ^ (((p >> 7) & 7) << 4);
            int r  = lg >> 7, cb = lg & 127;
            gload16((const char*)(A  + (size_t)(row0 + r) * E_DIM + k0) + cb, Ab + i * 4096 + w * 1024);
            gload16((const char*)(Bt + (size_t)(col0 + r) * E_DIM + k0) + cb, Bb + i * 4096 + w * 1024);
        }
    };

    stage(0, 0);
    for (int kt = 0; kt < 6; ++kt) {
        __syncthreads();
        if (kt < 5) stage((kt + 1) & 1, (kt + 1) * 64);
        const char* Ab = lds + (kt & 1) * 32768;
        const char* Bb = Ab + 16384;
#pragma unroll
        for (int ks = 0; ks < 2; ++ks) {
            bf16x8 af[4], bfr[4];
#pragma unroll
            for (int mi = 0; mi < 4; ++mi) {
                int rl = wm * 64 + mi * 16 + (lane & 15);
                int lg = rl * 128 + ks * 64 + ((lane >> 4) << 4);
                int ph = lg ^ ((rl & 7) << 4);
                af[mi] = *(const bf16x8*)(Ab + ph);
            }
#pragma unroll
            for (int ni = 0; ni < 4; ++ni) {
                int rl = wn * 64 + ni * 16 + (lane & 15);
                int lg = rl * 128 + ks * 64 + ((lane >> 4) << 4);
                int ph = lg ^ ((rl & 7) << 4);
                bfr[ni] = *(const bf16x8*)(Bb + ph);
            }
#pragma unroll
            for (int mi = 0; mi < 4; ++mi)
#pragma unroll
                for (int ni = 0; ni < 4; ++ni)
                    acc[mi][ni] = __builtin_amdgcn_mfma_f32_16x16x32_bf16(
                        af[mi], bfr[ni], acc[mi][ni], 0, 0, 0);
        }
    }

#pragma unroll
    for (int mi = 0; mi < 4; ++mi) {
#pragma unroll
        for (int ni = 0; ni < 4; ++ni) {
            int gcl = col0 + wn * 64 + ni * 16 + (lane & 15);   // 0..1151
            int which = gcl / 384;
            int rem = gcl - which * 384;
            int h = rem >> 6, d = rem & 63;
            int gr0 = row0 + wm * 64 + mi * 16 + ((lane >> 4) << 2);
#pragma unroll
            for (int j = 0; j < 4; ++j) {
                int gr = gr0 + j;
                int b = gr >> 8, t = gr & 255;
                int bh = b * N_HEAD + h;
                __hip_bfloat16 v = __float2bfloat16(acc[mi][ni][j]);
                if (which == 0)      qb[(((size_t)bh << 8) + t) * 64 + d] = v;
                else if (which == 1) kb[(((size_t)bh << 8) + t) * 64 + d] = v;
                else                 vt[(((size_t)bh << 6) + d) * SEQ + t] = v;
            }
        }
    }
}

// ---------------- fused layer tail: proj+res+LN2+MLP+res+LN(next) -----------
__global__ __launch_bounds__(256) void tail_fused(const __hip_bfloat16* __restrict__ A,
                                                  const __hip_bfloat16* __restrict__ WoT,
                                                  const float* __restrict__ bo,
                                                  const __hip_bfloat16* __restrict__ WmT,
                                                  const float* __restrict__ bm,
                                                  const float* __restrict__ xin,
                                                  float* __restrict__ xout,
                                                  const float* __restrict__ g2,
                                                  const float* __restrict__ b2v,
                                                  const float* __restrict__ gn,
                                                  const float* __restrict__ bnv,
                                                  __hip_bfloat16* __restrict__ hout) {
    __shared__ __align__(1024) char lds[131072];
    char* Bbuf = lds;                       // + buf*49152
    char* Abuf = lds + 98304;               // + buf*4096
    float* xt  = (float*)(lds + 49152);
    char* h2   = lds + 106496;              // [32 rows][768B], XOR-swizzled
    int tid = threadIdx.x;
    int lane = tid & 63, w = tid >> 6;
    int row0 = blockIdx.x * 32;

    float xnew[2][6][4];
#pragma unroll
    for (int mi = 0; mi < 2; ++mi)
#pragma unroll
        for (int ni = 0; ni < 6; ++ni) {
            int gc = w * 96 + ni * 16 + (lane & 15);
            int lr0 = mi * 16 + ((lane >> 4) << 2);
#pragma unroll
            for (int j = 0; j < 4; ++j)
                xnew[mi][ni][j] = xin[(size_t)(row0 + lr0 + j) * E_DIM + gc];
        }

    f32x4 acc[2][6];
#pragma unroll
    for (int i = 0; i < 2; ++i)
#pragma unroll
        for (int j = 0; j < 6; ++j) acc[i][j] = (f32x4){0.f, 0.f, 0.f, 0.f};

    auto stageB = [&](const __hip_bfloat16* Bt, int buf, int k0) {
        char* Bb = Bbuf + buf * 49152;
#pragma unroll
        for (int i = 0; i < 12; ++i) {
            int p  = i * 4096 + tid * 16;
            int lg = p ^ (((p >> 7) & 7) << 4);
            int r  = lg >> 7, cb = lg & 127;
            gload16((const char*)(Bt + (size_t)r * E_DIM + k0) + cb, Bb + i * 4096 + w * 1024);
        }
    };
    auto stageA = [&](int buf, int k0) {
        int p  = tid * 16;
        int lg = p ^ (((p >> 7) & 7) << 4);
        int r  = lg >> 7, cb = lg & 127;
        gload16((const char*)(A + (size_t)(row0 + r) * E_DIM + k0) + cb,
                Abuf + buf * 4096 + w * 1024);
    };

    // ================= proj GEMM =================
    stageA(0, 0);
    stageB(WoT, 0, 0);
    for (int kt = 0; kt < 6; ++kt) {
        __syncthreads();
        if (kt < 5) { stageA((kt + 1) & 1, (kt + 1) * 64); stageB(WoT, (kt + 1) & 1, (kt + 1) * 64); }
        const char* Ab = Abuf + (kt & 1) * 4096;
        const char* Bb = Bbuf + (kt & 1) * 49152;
#pragma unroll
        for (int ks = 0; ks < 2; ++ks) {
            bf16x8 af[2], bfr[6];
#pragma unroll
            for (int mi = 0; mi < 2; ++mi) {
                int rl = mi * 16 + (lane & 15);
                int lg = rl * 128 + ks * 64 + ((lane >> 4) << 4);
                int ph = lg ^ ((rl & 7) << 4);
                af[mi] = *(const bf16x8*)(Ab + ph);
            }
#pragma unroll
            for (int ni = 0; ni < 6; ++ni) {
                int rl = w * 96 + ni * 16 + (lane & 15);
                int lg = rl * 128 + ks * 64 + ((lane >> 4) << 4);
                int ph = lg ^ ((rl & 7) << 4);
                bfr[ni] = *(const bf16x8*)(Bb + ph);
            }
#pragma unroll
            for (int mi = 0; mi < 2; ++mi)
#pragma unroll
                for (int ni = 0; ni < 6; ++ni)
                    acc[mi][ni] = __builtin_amdgcn_mfma_f32_16x16x32_bf16(
                        af[mi], bfr[ni], acc[mi][ni], 0, 0, 0);
        }
    }
    __syncthreads();
    stageB(WmT, 0, 0);          // prefetch Wm chunk0 under LN2

#pragma unroll
    for (int mi = 0; mi < 2; ++mi) {
#pragma unroll
        for (int ni = 0; ni < 6; ++ni) {
            int gc = w * 96 + ni * 16 + (lane & 15);
            int lr0 = mi * 16 + ((lane >> 4) << 2);
            float bv = bo[gc];
#pragma unroll
            for (int j = 0; j < 4; ++j) {
                float xn = xnew[mi][ni][j] + acc[mi][ni][j] + bv;
                xnew[mi][ni][j] = xn;
                xt[(lr0 + j) * 392 + gc] = xn;
            }
        }
    }
    __syncthreads();

#pragma unroll
    for (int r8 = 0; r8 < 8; ++r8) {
        int r = w * 8 + r8;
        float v[6];
        float s = 0.f;
#pragma unroll
        for (int c = 0; c < 6; ++c) { v[c] = xt[r * 392 + lane + 64 * c]; s += v[c]; }
#pragma unroll
        for (int off = 32; off > 0; off >>= 1) s += __shfl_xor(s, off);
        float mu = s * (1.0f / E_DIM);
        float s2 = 0.f;
#pragma unroll
        for (int c = 0; c < 6; ++c) { float d = v[c] - mu; s2 += d * d; }
#pragma unroll
        for (int off = 32; off > 0; off >>= 1) s2 += __shfl_xor(s2, off);
        float rstd = rsqrtf(s2 * (1.0f / E_DIM) + 1e-5f);
#pragma unroll
        for (int c = 0; c < 6; ++c) {
            int e = lane + 64 * c;
            unsigned short u = bfbits((v[c] - mu) * rstd * g2[e] + b2v[e]);
            int by = (2 * e) ^ ((r & 7) << 4);
            *(unsigned short*)(h2 + r * 768 + by) = u;
        }
    }

    // ================= MLP GEMM (A from h2 LDS) =================
#pragma unroll
    for (int i = 0; i < 2; ++i)
#pragma unroll
        for (int j = 0; j < 6; ++j) acc[i][j] = (f32x4){0.f, 0.f, 0.f, 0.f};

    for (int kt = 0; kt < 6; ++kt) {
        __syncthreads();
        if (kt < 5) stageB(WmT, (kt + 1) & 1, (kt + 1) * 64);
        const char* Bb = Bbuf + (kt & 1) * 49152;
#pragma unroll
        for (int ks = 0; ks < 2; ++ks) {
            bf16x8 af[2], bfr[6];
#pragma unroll
            for (int mi = 0; mi < 2; ++mi) {
                int rl = mi * 16 + (lane & 15);
                int koff = kt * 128 + ks * 64 + ((lane >> 4) << 4);
                int by = koff ^ ((rl & 7) << 4);
                af[mi] = *(const bf16x8*)(h2 + rl * 768 + by);
            }
#pragma unroll
            for (int ni = 0; ni < 6; ++ni) {
                int rl = w * 96 + ni * 16 + (lane & 15);
                int lg = rl * 128 + ks * 64 + ((lane >> 4) << 4);
                int ph = lg ^ ((rl & 7) << 4);
                bfr[ni] = *(const bf16x8*)(Bb + ph);
            }
#pragma unroll
            for (int mi = 0; mi < 2; ++mi)
#pragma unroll
                for (int ni = 0; ni < 6; ++ni)
                    acc[mi][ni] = __builtin_amdgcn_mfma_f32_16x16x32_bf16(
                        af[mi], bfr[ni], acc[mi][ni], 0, 0, 0);
        }
    }
    __syncthreads();

#pragma unroll
    for (int mi = 0; mi < 2; ++mi) {
#pragma unroll
        for (int ni = 0; ni < 6; ++ni) {
            int gc = w * 96 + ni * 16 + (lane & 15);
            int lr0 = mi * 16 + ((lane >> 4) << 2);
            float bv = bm[gc];
#pragma unroll
            for (int j = 0; j < 4; ++j) {
                float u = fmaxf(acc[mi][ni][j] + bv, 0.f);
                float xn = xnew[mi][ni][j] + u;
                xout[(size_t)(row0 + lr0 + j) * E_DIM + gc] = xn;
                xt[(lr0 + j) * 392 + gc] = xn;
            }
        }
    }
    __syncthreads();

#pragma unroll
    for (int r8 = 0; r8 < 8; ++r8) {
        int r = w * 8 + r8;
        float v[6];
        float s = 0.f;
#pragma unroll
        for (int c = 0; c < 6; ++c) { v[c] = xt[r * 392 + lane + 64 * c]; s += v[c]; }
#pragma unroll
        for (int off = 32; off > 0; off >>= 1) s += __shfl_xor(s, off);
        float mu = s * (1.0f / E_DIM);
        float s2 = 0.f;
#pragma unroll
        for (int c = 0; c < 6; ++c) { float d = v[c] - mu; s2 += d * d; }
#pragma unroll
        for (int off = 32; off > 0; off >>= 1) s2 += __shfl_xor(s2, off);
        float rstd = rsqrtf(s2 * (1.0f / E_DIM) + 1e-5f);
        __hip_bfloat16* hr = hout + (size_t)(row0 + r) * E_DIM;
#pragma unroll
        for (int c = 0; c < 6; ++c) {
            int e = lane + 64 * c;
            hr[e] = __float2bfloat16((v[c] - mu) * rstd * gn[e] + bnv[e]);
        }
    }
}

// ---------------- LM-head GEMM: 8-wave low-AGPR + LDS row-linear epilogue ------
// K-loop identical to R13 (best). Epilogue change only: acc(+bias) -> LDS f32
// tile [128][132], then row-linear writeout where each half-wave store covers
// 128B contiguous (vs 4 rows x 64B scattered). Targets the odd-row-stride
// (50257*4 % 16 == 4) store-coalescing loss. Values bitwise identical.
__global__ __launch_bounds__(512) void mgemm_lm(const __hip_bfloat16* __restrict__ A,
                                                const __hip_bfloat16* __restrict__ Bt,
                                                const float* __restrict__ bias,
                                                float* __restrict__ C) {
    __shared__ __align__(1024) char lds[67584];   // staging 32K; f32 tile [128][132] after
    char* Ar = lds;
    char* Br = lds + 16384;
    float* tile = (float*)lds;
    int tid = threadIdx.x;
    int lane = tid & 63, w = tid >> 6;            // 8 waves
    int wm = w >> 2, wn = w & 3;                  // 2 x 4 -> each wave 64r x 32c

    // bijective XCD swizzle: grid 393x32 = 12576 = 8*1572, bx-major within XCD
    int wg  = blockIdx.y * 393 + blockIdx.x;
    int swz = (wg & 7) * 1572 + (wg >> 3);
    int bx  = swz % 393, by = swz / 393;
    int row0 = by * 128;
    int col0 = bx * 128;

    f32x4 acc[4][2];
#pragma unroll
    for (int i = 0; i < 4; ++i)
#pragma unroll
        for (int j = 0; j < 2; ++j) acc[i][j] = (f32x4){0.f, 0.f, 0.f, 0.f};

    for (int k0 = 0; k0 < E_DIM; k0 += 64) {
        __syncthreads();
#pragma unroll
        for (int i = 0; i < 2; ++i) {   // A: 16KB
            int p  = i * 8192 + tid * 16;
            int lg = p ^ (((p >> 7) & 7) << 4);
            int r  = lg >> 7, cb = lg & 127;
            gload16((const char*)(A  + (size_t)(row0 + r) * E_DIM + k0) + cb, Ar + i * 8192 + w * 1024);
        }
#pragma unroll
        for (int i = 0; i < 2; ++i) {   // B: 16KB
            int p  = i * 8192 + tid * 16;
            int lg = p ^ (((p >> 7) & 7) << 4);
            int r  = lg >> 7, cb = lg & 127;
            gload16((const char*)(Bt + (size_t)(col0 + r) * E_DIM + k0) + cb, Br + i * 8192 + w * 1024);
        }
        __syncthreads();
#pragma unroll
        for (int ks = 0; ks < 2; ++ks) {
            bf16x8 af[4], bfr[2];
#pragma unroll
            for (int mi = 0; mi < 4; ++mi) {
                int rl = wm * 64 + mi * 16 + (lane & 15);
                int lg = rl * 128 + ks * 64 + ((lane >> 4) << 4);
                int ph = lg ^ ((rl & 7) << 4);
                af[mi] = *(const bf16x8*)(Ar + ph);
            }
#pragma unroll
            for (int ni = 0; ni < 2; ++ni) {
                int rl = wn * 32 + ni * 16 + (lane & 15);
                int lg = rl * 128 + ks * 64 + ((lane >> 4) << 4);
                int ph = lg ^ ((rl & 7) << 4);
                bfr[ni] = *(const bf16x8*)(Br + ph);
            }
#pragma unroll
            for (int mi = 0; mi < 4; ++mi)
#pragma unroll
                for (int ni = 0; ni < 2; ++ni)
                    acc[mi][ni] = __builtin_amdgcn_mfma_f32_16x16x32_bf16(
                        af[mi], bfr[ni], acc[mi][ni], 0, 0, 0);
        }
    }

    __syncthreads();   // staging reads done; tile overwrites LDS
    // acc + bias -> LDS tile (same single f32 add as the old direct epilogue)
#pragma unroll
    for (int mi = 0; mi < 4; ++mi) {
#pragma unroll
        for (int ni = 0; ni < 2; ++ni) {
            int lr = wm * 64 + mi * 16 + ((lane >> 4) << 2);
            int lc = wn * 32 + ni * 16 + (lane & 15);
            int gc = col0 + lc;
            float bv = (gc < VOCAB) ? bias[gc] : 0.f;
#pragma unroll
            for (int j = 0; j < 4; ++j)
                tile[(lr + j) * 132 + lc] = acc[mi][ni][j] + bv;
        }
    }
    __syncthreads();

    // row-linear writeout: pass covers 16 rows; half-wave = 128B contiguous
#pragma unroll
    for (int pass = 0; pass < 8; ++pass) {
        int r  = pass * 16 + (tid >> 5);
        int c0 = tid & 31;
        float* Cr = C + (size_t)(row0 + r) * VOCAB;
        const float* Tr = tile + r * 132;
#pragma unroll
        for (int u = 0; u < 4; ++u) {
            int lc = c0 + u * 32;
            int gc = col0 + lc;
            if (gc < VOCAB) Cr[gc] = Tr[lc];
        }
    }
}

// ---------------- fused MFMA attention (72 KB LDS, P aliases K) -------
#define ATT_K 0
#define ATT_V 32768
#define ATT_Q 65536

__global__ __launch_bounds__(256) void attn_fused(const __hip_bfloat16* __restrict__ qb,
                                                  const __hip_bfloat16* __restrict__ kb,
                                                  const __hip_bfloat16* __restrict__ vt,
                                                  __hip_bfloat16* __restrict__ o) {
    __shared__ __align__(1024) char lds[73728];
    int tid = threadIdx.x;
    int lane = tid & 63, w = tid >> 6;
    int bh = blockIdx.x;
    int mq = blockIdx.y;
    int b = bh / N_HEAD, h = bh - b * N_HEAD;

    const char* kg = (const char*)(kb + (size_t)bh * SEQ * 64);
#pragma unroll
    for (int i = 0; i < 8; ++i) {
        int p = i * 4096 + tid * 16;
        int lg = p ^ (((p >> 7) & 7) << 4);
        gload16(kg + lg, lds + ATT_K + p);
    }
    const char* vg = (const char*)(vt + (size_t)bh * 64 * SEQ);
#pragma unroll
    for (int i = 0; i < 8; ++i) {
        int p = i * 4096 + tid * 16;
        int lg = p ^ (((p >> 9) & 7) << 4);
        gload16(vg + lg, lds + ATT_V + p);
    }
    const char* qg = (const char*)(qb + ((size_t)bh * SEQ + mq * 64) * 64);
#pragma unroll
    for (int i = 0; i < 2; ++i) {
        int p = i * 4096 + tid * 16;
        int lg = p ^ (((p >> 7) & 7) << 4);
        gload16(qg + lg, lds + ATT_Q + p);
    }
    __syncthreads();

    int q0 = w * 16;
    int qg0 = mq * 64 + q0;

    f32x4 acc[16];
#pragma unroll
    for (int n = 0; n < 16; ++n) acc[n] = (f32x4){0.f, 0.f, 0.f, 0.f};
#pragma unroll
    for (int ks = 0; ks < 2; ++ks) {
        int rq = q0 + (lane & 15);
        int byq = (ks * 64 + ((lane >> 4) << 4)) ^ ((rq & 7) << 4);
        bf16x8 aq = *(const bf16x8*)(lds + ATT_Q + rq * 128 + byq);
#pragma unroll
        for (int n = 0; n < 16; ++n) {
            int rk = n * 16 + (lane & 15);
            int byk = (ks * 64 + ((lane >> 4) << 4)) ^ ((rk & 7) << 4);
            bf16x8 bk = *(const bf16x8*)(lds + ATT_K + rk * 128 + byk);
            acc[n] = __builtin_amdgcn_mfma_f32_16x16x32_bf16(aq, bk, acc[n], 0, 0, 0);
        }
    }
    __syncthreads();   // all K reads done; P may overwrite K region

    char* pbase = lds + ATT_K + w * 8192;   // per-wave [16][256] bf16
#pragma unroll
    for (int j = 0; j < 4; ++j) {
        int rql = ((lane >> 4) << 2) + j;
        int rg = qg0 + rql;
        float s[16];
        float m = -INFINITY;
#pragma unroll
        for (int n = 0; n < 16; ++n) {
            int cg = n * 16 + (lane & 15);
            float v = (cg <= rg) ? acc[n][j] * 0.125f : -INFINITY;
            s[n] = v;
            m = fmaxf(m, v);
        }
#pragma unroll
        for (int off = 1; off < 16; off <<= 1) m = fmaxf(m, __shfl_xor(m, off));
        float sum = 0.f;
#pragma unroll
        for (int n = 0; n < 16; ++n) { s[n] = __expf(s[n] - m); sum += s[n]; }
#pragma unroll
        for (int off = 1; off < 16; off <<= 1) sum += __shfl_xor(sum, off);
        float inv = 1.0f / sum;
#pragma unroll
        for (int n = 0; n < 16; ++n) {
            int cg = n * 16 + (lane & 15);
            int by = (cg * 2) ^ ((rql & 7) << 4);
            *(__hip_bfloat16*)(pbase + rql * 512 + by) = __float2bfloat16(s[n] * inv);
        }
    }

    f32x4 oacc[4];
#pragma unroll
    for (int nf = 0; nf < 4; ++nf) oacc[nf] = (f32x4){0.f, 0.f, 0.f, 0.f};
#pragma unroll
    for (int ks = 0; ks < 8; ++ks) {
        int rp = lane & 15;
        int byp = (ks * 64 + ((lane >> 4) << 4)) ^ ((rp & 7) << 4);
        bf16x8 ap = *(const bf16x8*)(pbase + rp * 512 + byp);
#pragma unroll
        for (int nf = 0; nf < 4; ++nf) {
            int rv = nf * 16 + (lane & 15);
            int byv = (ks * 64 + ((lane >> 4) << 4)) ^ ((rv & 7) << 4);
            bf16x8 bv = *(const bf16x8*)(lds + ATT_V + rv * 512 + byv);
            oacc[nf] = __builtin_amdgcn_mfma_f32_16x16x32_bf16(ap, bv, oacc[nf], 0, 0, 0);
        }
    }

#pragma unroll
    for (int nf = 0; nf < 4; ++nf) {
#pragma unroll
        for (int j = 0; j < 4; ++j) {
            int t = mq * 64 + q0 + ((lane >> 4) << 2) + j;
            int d = nf * 16 + (lane & 15);
            o[(size_t)(b * SEQ + t) * E_DIM + h * 64 + d] = __float2bfloat16(oacc[nf][j]);
        }
    }
}

extern "C" void kernel_launch(void* const* d_in, const int* in_sizes, int n_in,
                              void* d_out, int out_size, void* d_ws, size_t ws_size,
                              hipStream_t stream) {
    const int*   idx  = (const int*)d_in[0];
    const float* tok  = (const float*)d_in[1];
    const float* pos  = (const float*)d_in[2];
    const float* Wq   = (const float*)d_in[3];
    const float* Wk   = (const float*)d_in[4];
    const float* Wv   = (const float*)d_in[5];
    const float* Wo   = (const float*)d_in[6];
    const float* bo   = (const float*)d_in[7];
    const float* ln1g = (const float*)d_in[8];
    const float* ln1b = (const float*)d_in[9];
    const float* ln2g = (const float*)d_in[10];
    const float* ln2b = (const float*)d_in[11];
    const float* Wm   = (const float*)d_in[12];
    const float* bm   = (const float*)d_in[13];
    const float* lnfg = (const float*)d_in[14];
    const float* lnfb = (const float*)d_in[15];
    const float* Wlm  = (const float*)d_in[16];
    const float* blm  = (const float*)d_in[17];
    float* out = (float*)d_out;

    float*           x    = (float*)d_ws;                         // [4096][384] f32
    __hip_bfloat16*  hb   = (__hip_bfloat16*)(x + (size_t)NTOK * E_DIM);
    __hip_bfloat16*  WtL  = hb + (size_t)NTOK * E_DIM;
    __hip_bfloat16*  WtLM = WtL + (size_t)NLAYER * 1920 * E_DIM;  // [50304][384]
    __hip_bfloat16*  qbv  = WtLM + (size_t)VPAD * E_DIM;
    __hip_bfloat16*  kbv  = qbv + (size_t)NBH * SEQ * 64;
    __hip_bfloat16*  vtb  = kbv + (size_t)NBH * SEQ * 64;

    prep_kernel<<<1080 + 786 * 6 + NTOK / 4, 256, 0, stream>>>(
        Wq, Wk, Wv, Wo, Wm, Wlm, WtL, WtLM, idx, tok, pos, ln1g, ln1b, x, hb);

    for (int l = 0; l < NLAYER; ++l) {
        const __hip_bfloat16* wl = WtL + (size_t)l * 1920 * E_DIM;
        qkvgemm<<<dim3(QKV_N / 128, NTOK / 128), 256, 0, stream>>>(hb, wl, qbv, kbv, vtb);
        attn_fused<<<dim3(NBH, 4), 256, 0, stream>>>(qbv, kbv, vtb, hb);
        const float* ng = (l == NLAYER - 1) ? lnfg : ln1g + (l + 1) * E_DIM;
        const float* nb = (l == NLAYER - 1) ? lnfb : ln1b + (l + 1) * E_DIM;
        tail_fused<<<NTOK / 32, 256, 0, stream>>>(hb, wl + (size_t)1152 * E_DIM,
                                                  bo + l * E_DIM,
                                                  wl + (size_t)1536 * E_DIM,
                                                  bm + l * E_DIM,
                                                  x, x,
                                                  ln2g + l * E_DIM, ln2b + l * E_DIM,
                                                  ng, nb, hb);
    }

    mgemm_lm<<<dim3(VPAD / 128, NTOK / 128), 512, 0, stream>>>(hb, WtLM, blm, out);
}